// Round 7
// baseline (388.130 us; speedup 1.0000x reference)
//
#include <hip/hip_runtime.h>
#include <hip/hip_bf16.h>

#define N_NODES     65536
#define N_EDGES     524288
#define N_GRAPHS    512
#define G_NODES_N   10000
#define NUM_DIS     2000
#define IN_DIM      128
#define HID         256
#define D_FEAT      512
#define MAX_Z       4000

typedef _Float16 half8 __attribute__((ext_vector_type(8)));
typedef float    f32x4 __attribute__((ext_vector_type(4)));

typedef __attribute__((address_space(1))) const void as1_void;
typedef __attribute__((address_space(3))) void       as3_void;

// ---------------------------------------------------------------------------
// 1. ONE prep dispatch: all weight converts/swizzles + zt16 + zn2 + zeroing.
//    zn2 stores BYTE offsets (z*256, node_id*256).
// ---------------------------------------------------------------------------
__global__ __launch_bounds__(256) void prep_kernel(
    const float* __restrict__ Ws, const float* __restrict__ Wn,
    const float* __restrict__ Wd, const float* __restrict__ Wc,
    const float* __restrict__ W1, const float* __restrict__ W2,
    const float* __restrict__ z_table,
    const int* __restrict__ z, const int* __restrict__ node_id,
    _Float16* __restrict__ WsT, _Float16* __restrict__ WnT,
    _Float16* __restrict__ WdT, _Float16* __restrict__ WcT,
    _Float16* __restrict__ W12P, _Float16* __restrict__ zt16,
    int2* __restrict__ zn2, int* __restrict__ cnt, int* __restrict__ flags)
{
    const int b = blockIdx.x;
    const int tid = threadIdx.x;
    if (b < 64) {
        __shared__ float tile[64][65];
        const float* W; _Float16* T; int K, N, k0, n0;
        if (b < 32) {
            const int mat = b >> 4, t = b & 15;
            K = HID; N = HID; k0 = (t >> 2) * 64; n0 = (t & 3) * 64;
            W = (mat == 0) ? Ws : Wn;
            T = (mat == 0) ? WsT : WnT;
        } else {
            const int bb = b - 32;
            const int mat = bb >> 4, t = bb & 15;
            K = D_FEAT; N = IN_DIM; k0 = (t >> 1) * 64; n0 = (t & 1) * 64;
            W = (mat == 0) ? Wd : Wc;
            T = (mat == 0) ? WdT : WcT;
        }
        const int tx = tid & 63, ty = tid >> 6;
        #pragma unroll
        for (int r = 0; r < 64; r += 4)
            tile[r + ty][tx] = W[(size_t)(k0 + r + ty) * N + n0 + tx];
        __syncthreads();
        #pragma unroll
        for (int c = 0; c < 64; c += 4)
            T[(size_t)(n0 + c + ty) * K + k0 + tx] = (_Float16)tile[tx][c + ty];
    } else if (b < 576) {
        const int bb = b - 64;              // 0..511
        const int mat = bb >> 8;            // 0: W1, 1: W2
        const int k = bb & 255;
        const int n = tid;
        const float* W = mat ? W2 : W1;
        const float v = W[(size_t)k * HID + n];
        const size_t idx = (size_t)(mat * 8 + (k >> 5)) * 8192
                         + (size_t)((((k >> 3) & 3) * 256 + n) * 8 + (k & 7));
        W12P[idx] = (_Float16)v;
    } else if (b < 826) {
        const size_t base = ((size_t)(b - 576) * 256 + tid) * 8;  // < 512000
        const float4 f0 = *(const float4*)(z_table + base);
        const float4 f1 = *(const float4*)(z_table + base + 4);
        half8 h;
        h[0]=(_Float16)f0.x; h[1]=(_Float16)f0.y; h[2]=(_Float16)f0.z; h[3]=(_Float16)f0.w;
        h[4]=(_Float16)f1.x; h[5]=(_Float16)f1.y; h[6]=(_Float16)f1.z; h[7]=(_Float16)f1.w;
        *(half8*)(zt16 + base) = h;
    } else if (b < 890) {
        const int base = (b - 826) * 1024 + tid * 4;
        *(int4*)(cnt + base) = make_int4(0, 0, 0, 0);
        if (b == 826 && tid < 128) flags[tid] = 0;
    } else {
        const int i = (b - 890) * 256 + tid;
        zn2[i] = make_int2(z[i] << 8, node_id[i] << 8);   // byte offsets
    }
}

// ---------------------------------------------------------------------------
// 2. Projection GEMM (MFMA, blocks 0..78) merged with edge histogram.
// ---------------------------------------------------------------------------
__global__ __launch_bounds__(256) void proj_hist_kernel(
    const float* __restrict__ dtab, const float* __restrict__ ctab,
    const _Float16* __restrict__ WdT, const _Float16* __restrict__ WcT,
    _Float16* __restrict__ proj,
    const int* __restrict__ dst, int* __restrict__ cnt)
{
    const int blk = blockIdx.x;
    if (blk >= 79) {
        const int e = (blk - 79) * 256 + threadIdx.x;
        if (e < N_EDGES) atomicAdd(&cnt[dst[e]], 1);
        return;
    }
    __shared__ _Float16 Alds[128 * 40];
    __shared__ _Float16 Blds[128 * 40];
    const float* tab; const _Float16* WT; int base, M, bm;
    if (blk < 16) { tab = dtab; WT = WdT; base = 0;           M = NUM_DIS + 1;             bm = blk * 128; }
    else          { tab = ctab; WT = WcT; base = NUM_DIS + 1; M = G_NODES_N - NUM_DIS - 1; bm = (blk - 16) * 128; }
    const int tid  = threadIdx.x;
    const int wave = tid >> 6, lane = tid & 63;
    const int q    = lane >> 4, l16 = lane & 15;
    const int mbase = (wave & 1) * 64, nbase = (wave >> 1) * 64;
    const int r = tid >> 1, s = tid & 1;

    f32x4 acc[4][4] = {};

    for (int kc = 0; kc < 16; ++kc) {
        const int k0 = kc * 32;
        const int arow = min(bm + r, M - 1);
        const float* gA = tab + (size_t)(base + arow) * D_FEAT + k0 + s * 16;
        const _Float16* gB = WT + (size_t)r * D_FEAT + k0 + s * 16;
        const float4 f0 = ((const float4*)gA)[0];
        const float4 f1 = ((const float4*)gA)[1];
        const float4 f2 = ((const float4*)gA)[2];
        const float4 f3 = ((const float4*)gA)[3];
        const half8 hb0 = *(const half8*)gB;
        const half8 hb1 = *(const half8*)(gB + 8);
        half8 h0, h1;
        h0[0]=(_Float16)f0.x; h0[1]=(_Float16)f0.y; h0[2]=(_Float16)f0.z; h0[3]=(_Float16)f0.w;
        h0[4]=(_Float16)f1.x; h0[5]=(_Float16)f1.y; h0[6]=(_Float16)f1.z; h0[7]=(_Float16)f1.w;
        h1[0]=(_Float16)f2.x; h1[1]=(_Float16)f2.y; h1[2]=(_Float16)f2.z; h1[3]=(_Float16)f2.w;
        h1[4]=(_Float16)f3.x; h1[5]=(_Float16)f3.y; h1[6]=(_Float16)f3.z; h1[7]=(_Float16)f3.w;
        __syncthreads();
        *(half8*)&Alds[r * 40 + s * 16]     = h0;
        *(half8*)&Alds[r * 40 + s * 16 + 8] = h1;
        *(half8*)&Blds[r * 40 + s * 16]     = hb0;
        *(half8*)&Blds[r * 40 + s * 16 + 8] = hb1;
        __syncthreads();
        half8 a[4], b[4];
        #pragma unroll
        for (int i = 0; i < 4; ++i)
            a[i] = *(const half8*)&Alds[(mbase + i * 16 + l16) * 40 + q * 8];
        #pragma unroll
        for (int j = 0; j < 4; ++j)
            b[j] = *(const half8*)&Blds[(nbase + j * 16 + l16) * 40 + q * 8];
        #pragma unroll
        for (int i = 0; i < 4; ++i)
            #pragma unroll
            for (int j = 0; j < 4; ++j)
                acc[i][j] = __builtin_amdgcn_mfma_f32_16x16x32_f16(a[i], b[j], acc[i][j], 0, 0, 0);
    }

    #pragma unroll
    for (int j = 0; j < 4; ++j) {
        const int colg = nbase + j * 16 + l16;   // 0..127
        #pragma unroll
        for (int i = 0; i < 4; ++i) {
            #pragma unroll
            for (int rr = 0; rr < 4; ++rr) {
                const int row = bm + mbase + i * 16 + q * 4 + rr;
                if (row < M)
                    proj[(size_t)(base + row) * IN_DIM + colg] = (_Float16)acc[i][j][rr];
            }
        }
    }
}

// ---------------------------------------------------------------------------
// 3. CSR build + DEGREE-SORT (64-bucket counting sort over 2 rendezvous).
// ---------------------------------------------------------------------------
__global__ __launch_bounds__(256) void scan_fused_kernel(
    const int* __restrict__ cnt, int* __restrict__ row_ptr,
    int* __restrict__ fill, int* __restrict__ flags,
    const int2* __restrict__ zn2, int2* __restrict__ pzn,
    int2* __restrict__ prbe, int* __restrict__ pnode,
    int* __restrict__ bhist)
{
    __shared__ int a[256], b[256];
    __shared__ int sums[64];
    __shared__ int segbase;
    __shared__ int hist[64];
    __shared__ int pos[64];
    const int t = threadIdx.x;
    const int blk = blockIdx.x;
    const int base = blk * 1024 + t * 4;
    const int4 c = *(const int4*)(cnt + base);
    const int s = c.x + c.y + c.z + c.w;
    a[t] = s;
    if (t < 64) hist[t] = 0;
    __syncthreads();
    int* in = a; int* out = b;
    for (int off = 1; off < 256; off <<= 1) {
        out[t] = in[t] + ((t >= off) ? in[t - off] : 0);
        __syncthreads();
        int* tmp = in; in = out; out = tmp;
    }
    if (t == 0) {
        atomicExch(&flags[64 + blk], in[255]);
        __threadfence();
        atomicAdd(&flags[0], 1);
        while (atomicAdd(&flags[0], 0) < 64) {}
    }
    __syncthreads();
    if (t < 64) sums[t] = atomicAdd(&flags[64 + t], 0);
    __syncthreads();
    if (t == 0) {
        int pfx = 0;
        for (int i = 0; i < blk; ++i) pfx += sums[i];
        segbase = pfx;
        if (blk == 63) {
            int tot = pfx;
            for (int i = blk; i < 64; ++i) tot += sums[i];
            row_ptr[N_NODES] = tot;
        }
    }
    __syncthreads();
    const int run = in[t] - s + segbase;
    int4 r;
    r.x = run; r.y = run + c.x; r.z = r.y + c.y; r.w = r.z + c.z;
    *(int4*)(row_ptr + base) = r;
    *(int4*)(fill + base) = r;

    // ---- phase 2: degree counting sort ----
    const int bk0 = min(c.x, 63), bk1 = min(c.y, 63);
    const int bk2 = min(c.z, 63), bk3 = min(c.w, 63);
    atomicAdd(&hist[bk0], 1); atomicAdd(&hist[bk1], 1);
    atomicAdd(&hist[bk2], 1); atomicAdd(&hist[bk3], 1);
    __syncthreads();
    if (t < 64) bhist[blk * 64 + t] = hist[t];
    __threadfence();
    if (t == 0) {
        atomicAdd(&flags[1], 1);
        while (atomicAdd(&flags[1], 0) < 64) {}
    }
    __syncthreads();
    if (t < 64) {
        int pre = 0, tot = 0;
        for (int i = 0; i < 64; ++i) {
            const int v = atomicAdd(&bhist[i * 64 + t], 0);
            if (i < blk) pre += v;
            tot += v;
        }
        hist[t] = tot;   // bucket totals
        pos[t] = pre;    // this block's offset within bucket
    }
    __syncthreads();
    if (t == 0) {
        int run2 = 0;
        for (int i = 0; i < 64; ++i) { const int tt = hist[i]; hist[i] = run2; run2 += tt; }
    }
    __syncthreads();
    if (t < 64) pos[t] = hist[t] + pos[t];   // block's write cursor per bucket
    __syncthreads();
    const int begs[4] = { r.x, r.y, r.z, r.w };
    const int ends[4] = { r.y, r.z, r.w, r.w + c.w };
    const int bks[4]  = { bk0, bk1, bk2, bk3 };
    #pragma unroll
    for (int k = 0; k < 4; ++k) {
        const int p = atomicAdd(&pos[bks[k]], 1);
        pzn[p]   = zn2[base + k];
        prbe[p]  = make_int2(begs[k], ends[k]);
        pnode[p] = base + k;
    }
}

// Scatter: col stores BYTE offsets (src * 512) for csr_agg's H-row loads.
__global__ __launch_bounds__(256) void scatter_kernel(
    const int* __restrict__ src, const int* __restrict__ dst,
    const int2* __restrict__ zn2,
    int* __restrict__ fill, int* __restrict__ col, int2* __restrict__ colzn)
{
    const int e = blockIdx.x * 256 + threadIdx.x;
    if (e < N_EDGES) {
        const int s = src[e];
        const int pos = atomicAdd(&fill[dst[e]], 1);
        col[pos] = s << 9;              // byte offset into H (512 B/row)
        colzn[pos] = zn2[s];
    }
}

// ---------------------------------------------------------------------------
// 4a. Standalone GIN gather at HIGH occupancy: LDS-free, 16 lanes/row.
// ---------------------------------------------------------------------------
__global__ __launch_bounds__(256, 6) void gather_kernel(
    const int2* __restrict__ prbe, const int2* __restrict__ pzn,
    const int2* __restrict__ colzn,
    const _Float16* __restrict__ zt16, const _Float16* __restrict__ proj,
    _Float16* __restrict__ AGG)
{
    const int i = blockIdx.x * 16 + (threadIdx.x >> 4);   // sorted row
    const int l = threadIdx.x & 15;
    const bool isz = (l < 8);
    const char* tab = isz ? (const char*)zt16 : (const char*)proj;
    const int loff = (l & 7) * 32;
    const int2 be = prbe[i];
    const int2 zn = pzn[i];
    float acc[16];
    {
        const half8* sp = (const half8*)(tab + (isz ? zn.x : zn.y) + loff);
        const half8 v0 = sp[0], v1 = sp[1];
        #pragma unroll
        for (int k = 0; k < 8; ++k) { acc[k] = (float)v0[k]; acc[8 + k] = (float)v1[k]; }
    }
    int e = be.x;
    const int end = be.y;
    int2 iA, iB, iC, iD;
    if (e + 4 <= end) {
        iA = colzn[e]; iB = colzn[e + 1]; iC = colzn[e + 2]; iD = colzn[e + 3];
    }
    for (; e + 4 <= end; e += 4) {
        const half8* sA = (const half8*)(tab + (isz ? iA.x : iA.y) + loff);
        const half8* sB = (const half8*)(tab + (isz ? iB.x : iB.y) + loff);
        const half8* sC = (const half8*)(tab + (isz ? iC.x : iC.y) + loff);
        const half8* sD = (const half8*)(tab + (isz ? iD.x : iD.y) + loff);
        const half8 a0 = sA[0], a1 = sA[1];
        const half8 b0 = sB[0], b1 = sB[1];
        const half8 c0 = sC[0], c1 = sC[1];
        const half8 d0 = sD[0], d1 = sD[1];
        if (e + 8 <= end) {
            iA = colzn[e + 4]; iB = colzn[e + 5];
            iC = colzn[e + 6]; iD = colzn[e + 7];
        }
        #pragma unroll
        for (int k = 0; k < 8; ++k) {
            acc[k]     += ((float)a0[k] + (float)b0[k]) + ((float)c0[k] + (float)d0[k]);
            acc[8 + k] += ((float)a1[k] + (float)b1[k]) + ((float)c1[k] + (float)d1[k]);
        }
    }
    for (; e < end; ++e) {
        const int2 j = colzn[e];
        const half8* s = (const half8*)(tab + (isz ? j.x : j.y) + loff);
        const half8 v0 = s[0], v1 = s[1];
        #pragma unroll
        for (int k = 0; k < 8; ++k) { acc[k] += (float)v0[k]; acc[8 + k] += (float)v1[k]; }
    }
    half8 o0, o1;
    #pragma unroll
    for (int k = 0; k < 8; ++k) { o0[k] = (_Float16)acc[k]; o1[k] = (_Float16)acc[8 + k]; }
    _Float16* dst = AGG + (size_t)i * 256 + l * 16;
    *(half8*)dst = o0;
    *(half8*)(dst + 8) = o1;
}

// ---------------------------------------------------------------------------
// 4b. GIN MLP: dense A-stage from AGG (sorted order) + both GIN GEMMs.
// ---------------------------------------------------------------------------
__global__ __launch_bounds__(256) void gin_mlp_kernel(
    const _Float16* __restrict__ AGG, const int* __restrict__ pnode,
    const _Float16* __restrict__ W12P,
    const float* __restrict__ b1, const float* __restrict__ b2,
    _Float16* __restrict__ H)
{
    __shared__ _Float16 Apanel[64 * 264];   // 33792 B
    __shared__ _Float16 Blds[8192];         // 16384 B
    __shared__ int prows[64];

    const int bm   = blockIdx.x * 64;
    const int tid  = threadIdx.x;
    const int wave = tid >> 6, lane = tid & 63;
    const int q    = lane >> 4, l16 = lane & 15;
    const int nbase = wave * 64;
    const int sb   = wave * 256 + lane;

    if (tid < 64) prows[tid] = pnode[bm + tid];

    // chunk-0 DMA overlaps the A-stage
    #pragma unroll
    for (int tt = 0; tt < 4; ++tt) {
        const int seg = (wave * 4 + tt) * 64 + lane;
        __builtin_amdgcn_global_load_lds((as1_void*)(W12P + seg * 8),
            (as3_void*)&Blds[(wave * 4 + tt) * 64 * 8], 16, 0, 0);
    }

    // ---- A-stage: dense coalesced read of 64 sorted rows -> padded LDS ----
    {
        const int ar = tid >> 2, acs = (tid & 3) * 64;
        const _Float16* asrc = AGG + (size_t)(bm + ar) * 256 + acs;
        half8 av[8];
        #pragma unroll
        for (int k = 0; k < 8; ++k) av[k] = *(const half8*)(asrc + k * 8);
        #pragma unroll
        for (int k = 0; k < 8; ++k)
            *(half8*)&Apanel[ar * 264 + acs + k * 8] = av[k];
    }
    __syncthreads();   // A-stage + prows visible, chunk-0 DMA drained

    // ---- GEMM phase: reg-prefetch pipeline, single Blds buffer ----
    half8 pf0, pf1, pf2, pf3;
    auto pfetch = [&](int c) {
        const _Float16* s = W12P + (size_t)c * 8192 + (size_t)sb * 8;
        pf0 = *(const half8*)(s);
        pf1 = *(const half8*)(s + 512);
        pf2 = *(const half8*)(s + 1024);
        pf3 = *(const half8*)(s + 1536);
    };
    pfetch(1);

    f32x4 acc[4][4] = {};
    for (int c = 0; c < 16; ++c) {
        const int kl = (c & 7) * 32;
        half8 a[4], b[4];
        #pragma unroll
        for (int i = 0; i < 4; ++i)
            a[i] = *(const half8*)&Apanel[(i * 16 + l16) * 264 + kl + q * 8];
        #pragma unroll
        for (int j = 0; j < 4; ++j)
            b[j] = *(const half8*)&Blds[(q * 256 + nbase + j * 16 + l16) * 8];
        #pragma unroll
        for (int i = 0; i < 4; ++i)
            #pragma unroll
            for (int j = 0; j < 4; ++j)
                acc[i][j] = __builtin_amdgcn_mfma_f32_16x16x32_f16(a[i], b[j], acc[i][j], 0, 0, 0);
        if (c == 15) break;
        __syncthreads();                    // all waves done reading chunk c
        *(half8*)&Blds[sb * 8]         = pf0;   // write chunk c+1
        *(half8*)&Blds[(sb + 64) * 8]  = pf1;
        *(half8*)&Blds[(sb + 128) * 8] = pf2;
        *(half8*)&Blds[(sb + 192) * 8] = pf3;
        if (c == 7) {
            // H1 = relu(X@W1 + b1) writeback
            #pragma unroll
            for (int j = 0; j < 4; ++j) {
                const int colg = nbase + j * 16 + l16;
                const float bv = b1[colg];
                #pragma unroll
                for (int i = 0; i < 4; ++i)
                    #pragma unroll
                    for (int rr = 0; rr < 4; ++rr) {
                        const float v = fmaxf(acc[i][j][rr] + bv, 0.0f);
                        Apanel[(i * 16 + q * 4 + rr) * 264 + colg] = (_Float16)v;
                        acc[i][j][rr] = 0.0f;
                    }
            }
        }
        if (c < 14) pfetch(c + 2);          // loads fly over next MFMA
        __syncthreads();                    // chunk c+1 / Apanel visible
    }

    #pragma unroll
    for (int j = 0; j < 4; ++j) {
        const int colg = nbase + j * 16 + l16;
        const float bv = b2[colg];
        #pragma unroll
        for (int i = 0; i < 4; ++i)
            #pragma unroll
            for (int rr = 0; rr < 4; ++rr) {
                const int rowl = i * 16 + q * 4 + rr;
                H[(size_t)prows[rowl] * HID + colg] = (_Float16)(acc[i][j][rr] + bv);
            }
    }
}

// ---------------------------------------------------------------------------
// 5. MERGED dispatch: blocks 0..1023 = Ws-half GEMM (P = H@Ws + b, f32 out,
//    K=256, independent of AGG); blocks 1024..5119 = SAGE mean aggregation
//    (paired sorted rows). The GEMM's MFMA + streaming reads fill the pipes
//    the fabric-bound gather leaves idle.
// ---------------------------------------------------------------------------
__global__ __launch_bounds__(256) void agg_wsgemm_kernel(
    const int2* __restrict__ prbe, const int* __restrict__ pnode,
    const int* __restrict__ col,
    const _Float16* __restrict__ F, _Float16* __restrict__ OUT,
    const _Float16* __restrict__ WsT, const float* __restrict__ bias,
    float* __restrict__ P)
{
    __shared__ _Float16 Alds[128 * 32];
    __shared__ _Float16 Blds[128 * 32];
    const int blk = blockIdx.x;
    const int t = threadIdx.x;

    if (blk < 1024) {
        // ---- Ws-half GEMM: P[bm:bm+128, bn:bn+128] = H@WsT + bias ----
        const int bm   = (blk >> 1) * 128;
        const int bn   = (blk & 1) * 128;
        const int wave = t >> 6, lane = t & 63;
        const int q    = lane >> 4, l16 = lane & 15;
        const int mbase = (wave & 1) * 64, nbase = (wave >> 1) * 64;

        const int i0 = wave * 128 + lane;
        const int i1 = i0 + 64;
        const int r0 = i0 >> 2, s0 = i0 & 3;
        const int r1 = i1 >> 2, s1 = i1 & 3;

        half8 pa0, pa1, pb0, pb1;
        auto pfetch = [&](int kc) {
            const int k0 = kc * 32;
            pa0 = *(const half8*)(F + (size_t)(bm + r0) * HID + k0 + s0 * 8);
            pa1 = *(const half8*)(F + (size_t)(bm + r1) * HID + k0 + s1 * 8);
            pb0 = *(const half8*)(WsT + (size_t)(bn + r0) * HID + k0 + s0 * 8);
            pb1 = *(const half8*)(WsT + (size_t)(bn + r1) * HID + k0 + s1 * 8);
        };
        pfetch(0);

        f32x4 acc[4][4] = {};
        for (int kc = 0; kc < 8; ++kc) {
            __syncthreads();
            *(half8*)&Alds[i0 * 8] = pa0;
            *(half8*)&Alds[i1 * 8] = pa1;
            *(half8*)&Blds[i0 * 8] = pb0;
            *(half8*)&Blds[i1 * 8] = pb1;
            if (kc < 7) pfetch(kc + 1);
            __syncthreads();
            half8 a[4], b[4];
            #pragma unroll
            for (int i = 0; i < 4; ++i)
                a[i] = *(const half8*)&Alds[(mbase + i * 16 + l16) * 32 + q * 8];
            #pragma unroll
            for (int j = 0; j < 4; ++j)
                b[j] = *(const half8*)&Blds[(nbase + j * 16 + l16) * 32 + q * 8];
            #pragma unroll
            for (int i = 0; i < 4; ++i)
                #pragma unroll
                for (int j = 0; j < 4; ++j)
                    acc[i][j] = __builtin_amdgcn_mfma_f32_16x16x32_f16(a[i], b[j], acc[i][j], 0, 0, 0);
        }
        #pragma unroll
        for (int j = 0; j < 4; ++j) {
            const int colg = bn + nbase + j * 16 + l16;
            const float bv = bias[colg];
            #pragma unroll
            for (int i = 0; i < 4; ++i)
                #pragma unroll
                for (int rr = 0; rr < 4; ++rr) {
                    const int rowg = bm + mbase + i * 16 + q * 4 + rr;
                    P[(size_t)rowg * HID + colg] = acc[i][j][rr] + bv;
                }
        }
        return;
    }

    // ---- SAGE mean aggregation: 2 adjacent sorted rows per 32-lane group ----
    const int q = t & 31;
    const int pr = t >> 5;                        // 0..7
    const int ia = (blk - 1024) * 16 + pr * 2;
    const int ib = ia + 1;
    const int2 beA = prbe[ia];
    const int2 beB = prbe[ib];
    int eA = beA.x, eB = beB.x;
    const int endA = beA.y, endB = beB.y;
    const char* Fb = (const char*)F + q * 16;     // lane's 16B slice base
    float accA[8] = {0.f,0.f,0.f,0.f,0.f,0.f,0.f,0.f};
    float accB[8] = {0.f,0.f,0.f,0.f,0.f,0.f,0.f,0.f};

    int cA0, cA1, cA2, cA3, cB0, cB1, cB2, cB3;
    bool mA = (eA + 4 <= endA), mB = (eB + 4 <= endB);
    if (mA) { cA0 = col[eA]; cA1 = col[eA+1]; cA2 = col[eA+2]; cA3 = col[eA+3]; }
    if (mB) { cB0 = col[eB]; cB1 = col[eB+1]; cB2 = col[eB+2]; cB3 = col[eB+3]; }

    while (mA && mB) {
        const half8 a0 = *(const half8*)(Fb + cA0);
        const half8 a1 = *(const half8*)(Fb + cA1);
        const half8 a2 = *(const half8*)(Fb + cA2);
        const half8 a3 = *(const half8*)(Fb + cA3);
        const half8 b0 = *(const half8*)(Fb + cB0);
        const half8 b1 = *(const half8*)(Fb + cB1);
        const half8 b2 = *(const half8*)(Fb + cB2);
        const half8 b3 = *(const half8*)(Fb + cB3);
        eA += 4; eB += 4;
        mA = (eA + 4 <= endA); mB = (eB + 4 <= endB);
        if (mA) { cA0 = col[eA]; cA1 = col[eA+1]; cA2 = col[eA+2]; cA3 = col[eA+3]; }
        if (mB) { cB0 = col[eB]; cB1 = col[eB+1]; cB2 = col[eB+2]; cB3 = col[eB+3]; }
        #pragma unroll
        for (int k = 0; k < 8; ++k) {
            accA[k] += ((float)a0[k] + (float)a1[k]) + ((float)a2[k] + (float)a3[k]);
            accB[k] += ((float)b0[k] + (float)b1[k]) + ((float)b2[k] + (float)b3[k]);
        }
    }
    while (mA) {
        const half8 a0 = *(const half8*)(Fb + cA0);
        const half8 a1 = *(const half8*)(Fb + cA1);
        const half8 a2 = *(const half8*)(Fb + cA2);
        const half8 a3 = *(const half8*)(Fb + cA3);
        eA += 4;
        mA = (eA + 4 <= endA);
        if (mA) { cA0 = col[eA]; cA1 = col[eA+1]; cA2 = col[eA+2]; cA3 = col[eA+3]; }
        #pragma unroll
        for (int k = 0; k < 8; ++k)
            accA[k] += ((float)a0[k] + (float)a1[k]) + ((float)a2[k] + (float)a3[k]);
    }
    while (mB) {
        const half8 b0 = *(const half8*)(Fb + cB0);
        const half8 b1 = *(const half8*)(Fb + cB1);
        const half8 b2 = *(const half8*)(Fb + cB2);
        const half8 b3 = *(const half8*)(Fb + cB3);
        eB += 4;
        mB = (eB + 4 <= endB);
        if (mB) { cB0 = col[eB]; cB1 = col[eB+1]; cB2 = col[eB+2]; cB3 = col[eB+3]; }
        #pragma unroll
        for (int k = 0; k < 8; ++k)
            accB[k] += ((float)b0[k] + (float)b1[k]) + ((float)b2[k] + (float)b3[k]);
    }
    for (; eA < endA; ++eA) {
        const half8 v = *(const half8*)(Fb + col[eA]);
        #pragma unroll
        for (int k = 0; k < 8; ++k) accA[k] += (float)v[k];
    }
    for (; eB < endB; ++eB) {
        const half8 v = *(const half8*)(Fb + col[eB]);
        #pragma unroll
        for (int k = 0; k < 8; ++k) accB[k] += (float)v[k];
    }

    const float rsA = 1.0f / fmaxf((float)(endA - beA.x), 1.0f);
    const float rsB = 1.0f / fmaxf((float)(endB - beB.x), 1.0f);
    half8 oA, oB;
    #pragma unroll
    for (int k = 0; k < 8; ++k) {
        oA[k] = (_Float16)(accA[k] * rsA);
        oB[k] = (_Float16)(accB[k] * rsB);
    }
    *(half8*)(OUT + (size_t)pnode[ia] * HID + q * 8) = oA;
    *(half8*)(OUT + (size_t)pnode[ib] * HID + q * 8) = oB;
}

// ---------------------------------------------------------------------------
// 6. GEMM2: H2 = AGG@WnT + P (K=256, acc initialized from f32 P).
// ---------------------------------------------------------------------------
__global__ __launch_bounds__(256) void gemm2_kernel(
    const _Float16* __restrict__ A, const _Float16* __restrict__ BT,
    const float* __restrict__ P, _Float16* __restrict__ Ch)
{
    __shared__ _Float16 Alds[128 * 32];
    __shared__ _Float16 Blds[128 * 32];
    const int bm   = blockIdx.x * 128;
    const int bn   = blockIdx.y * 128;
    const int tid  = threadIdx.x;
    const int wave = tid >> 6, lane = tid & 63;
    const int q    = lane >> 4, l16 = lane & 15;
    const int mbase = (wave & 1) * 64, nbase = (wave >> 1) * 64;

    const int i0 = wave * 128 + lane;
    const int i1 = i0 + 64;
    const int r0 = i0 >> 2, s0 = i0 & 3;
    const int r1 = i1 >> 2, s1 = i1 & 3;

    half8 pa0, pa1, pb0, pb1;
    auto pfetch = [&](int kc) {
        const int k0 = kc * 32;
        pa0 = *(const half8*)(A + (size_t)(bm + r0) * HID + k0 + s0 * 8);
        pa1 = *(const half8*)(A + (size_t)(bm + r1) * HID + k0 + s1 * 8);
        pb0 = *(const half8*)(BT + (size_t)(bn + r0) * HID + k0 + s0 * 8);
        pb1 = *(const half8*)(BT + (size_t)(bn + r1) * HID + k0 + s1 * 8);
    };
    pfetch(0);

    // acc init from P (f32) — loads overlap the first LDS stage.
    f32x4 acc[4][4];
    #pragma unroll
    for (int j = 0; j < 4; ++j) {
        const int colg = bn + nbase + j * 16 + l16;
        #pragma unroll
        for (int i = 0; i < 4; ++i)
            #pragma unroll
            for (int rr = 0; rr < 4; ++rr) {
                const int rowg = bm + mbase + i * 16 + q * 4 + rr;
                acc[i][j][rr] = P[(size_t)rowg * HID + colg];
            }
    }

    for (int kc = 0; kc < 8; ++kc) {
        __syncthreads();
        *(half8*)&Alds[i0 * 8] = pa0;
        *(half8*)&Alds[i1 * 8] = pa1;
        *(half8*)&Blds[i0 * 8] = pb0;
        *(half8*)&Blds[i1 * 8] = pb1;
        if (kc < 7) pfetch(kc + 1);
        __syncthreads();
        half8 a[4], b[4];
        #pragma unroll
        for (int i = 0; i < 4; ++i)
            a[i] = *(const half8*)&Alds[(mbase + i * 16 + l16) * 32 + q * 8];
        #pragma unroll
        for (int j = 0; j < 4; ++j)
            b[j] = *(const half8*)&Blds[(nbase + j * 16 + l16) * 32 + q * 8];
        #pragma unroll
        for (int i = 0; i < 4; ++i)
            #pragma unroll
            for (int j = 0; j < 4; ++j)
                acc[i][j] = __builtin_amdgcn_mfma_f32_16x16x32_f16(a[i], b[j], acc[i][j], 0, 0, 0);
    }

    #pragma unroll
    for (int j = 0; j < 4; ++j) {
        const int colg = bn + nbase + j * 16 + l16;
        #pragma unroll
        for (int i = 0; i < 4; ++i) {
            #pragma unroll
            for (int rr = 0; rr < 4; ++rr) {
                const int rowg = bm + mbase + i * 16 + q * 4 + rr;
                Ch[(size_t)rowg * HID + colg] = (_Float16)acc[i][j][rr];
            }
        }
    }
}

// ---------------------------------------------------------------------------
// 7. Fused max-pool + head MLP: one block per graph.
// ---------------------------------------------------------------------------
__global__ __launch_bounds__(256) void pool_head_kernel(
    const _Float16* __restrict__ H2, const int* __restrict__ gid,
    const float* __restrict__ W1, const float* __restrict__ b1,
    const float* __restrict__ W2, const float* __restrict__ b2,
    float* __restrict__ out)
{
    const int g = blockIdx.x;
    const int tid = threadIdx.x;
    int lo = 0, hi = N_NODES;
    while (lo < hi) { const int mid = (lo + hi) >> 1; if (gid[mid] < g) lo = mid + 1; else hi = mid; }
    const int start = lo;
    hi = N_NODES;
    while (lo < hi) { const int mid = (lo + hi) >> 1; if (gid[mid] < g + 1) lo = mid + 1; else hi = mid; }
    const int end = lo;

    const int rowofs = tid >> 5;        // 0..7
    const int q = tid & 31;             // half8 col slice
    float m8[8];
    #pragma unroll
    for (int k = 0; k < 8; ++k) m8[k] = -INFINITY;
    for (int i = start + rowofs; i < end; i += 8) {
        const half8 v = *(const half8*)(H2 + (size_t)i * HID + q * 8);
        #pragma unroll
        for (int k = 0; k < 8; ++k) m8[k] = fmaxf(m8[k], (float)v[k]);
    }
    __shared__ float part[8][256];
    #pragma unroll
    for (int k = 0; k < 8; ++k) part[rowofs][q * 8 + k] = m8[k];
    __syncthreads();
    __shared__ float row[HID];
    __shared__ float red[HID];
    const int j = tid;
    float m = part[0][j];
    #pragma unroll
    for (int r = 1; r < 8; ++r) m = fmaxf(m, part[r][j]);
    row[j] = (m == -INFINITY) ? 0.0f : m;
    __syncthreads();
    float acc = b1[j];
    #pragma unroll 8
    for (int k = 0; k < HID; ++k)
        acc = fmaf(row[k], W1[k * HID + j], acc);
    acc = fmaxf(acc, 0.f);
    red[j] = acc * W2[j];
    __syncthreads();
    for (int s = 128; s > 0; s >>= 1) {
        if (j < s) red[j] += red[j + s];
        __syncthreads();
    }
    if (j == 0) out[g] = red[0] + b2[0];
}

// ---------------------------------------------------------------------------
extern "C" void kernel_launch(void* const* d_in, const int* in_sizes, int n_in,
                              void* d_out, int out_size, void* d_ws, size_t ws_size,
                              hipStream_t stream)
{
    const int*   z         = (const int*)d_in[0];
    const int*   node_id   = (const int*)d_in[1];
    const int*   src       = (const int*)d_in[2];
    const int*   dst       = (const int*)d_in[3];
    const int*   graph_ids = (const int*)d_in[4];
    const float* z_table   = (const float*)d_in[5];
    const float* d_feat    = (const float*)d_in[6];
    const float* c_feat    = (const float*)d_in[7];
    const float* Wd        = (const float*)d_in[8];
    const float* Wc        = (const float*)d_in[9];
    const float* gin_W1    = (const float*)d_in[10];
    const float* gin_b1    = (const float*)d_in[11];
    const float* gin_W2    = (const float*)d_in[12];
    const float* gin_b2    = (const float*)d_in[13];
    const float* sage_Wself  = (const float*)d_in[14];
    const float* sage_Wneigh = (const float*)d_in[15];
    const float* sage_b    = (const float*)d_in[16];
    const float* lin1_W    = (const float*)d_in[17];
    const float* lin1_b    = (const float*)d_in[18];
    const float* lin2_W    = (const float*)d_in[19];
    const float* lin2_b    = (const float*)d_in[20];
    float* out = (float*)d_out;

    // ---- workspace carve-up ----
    const size_t NH = (size_t)N_NODES * HID;
    char* wsb = (char*)d_ws;
    _Float16* Hh   = (_Float16*)wsb;                     wsb += NH * 2;
    _Float16* AGGh = (_Float16*)wsb;                     wsb += NH * 2;
    _Float16* H2h  = (_Float16*)wsb;                     wsb += NH * 2;
    _Float16* AGGx = (_Float16*)wsb;                     wsb += NH * 2;   // GIN gather output
    float* Pf32    = (float*)wsb;                        wsb += NH * 4;   // Ws-half GEMM out
    _Float16* projh= (_Float16*)wsb;                     wsb += (size_t)G_NODES_N * IN_DIM * 2;
    _Float16* W12P = (_Float16*)wsb;                     wsb += 16 * 8192 * 2;
    _Float16* WsT  = (_Float16*)wsb;                     wsb += HID * HID * 2;
    _Float16* WnT  = (_Float16*)wsb;                     wsb += HID * HID * 2;
    _Float16* WdT  = (_Float16*)wsb;                     wsb += D_FEAT * IN_DIM * 2;
    _Float16* WcT  = (_Float16*)wsb;                     wsb += D_FEAT * IN_DIM * 2;
    _Float16* zt16 = (_Float16*)wsb;                     wsb += (size_t)MAX_Z * IN_DIM * 2;
    int2* zn2      = (int2*)wsb;                         wsb += (size_t)N_NODES * 8;
    int2* colzn    = (int2*)wsb;                         wsb += (size_t)(N_EDGES + 8) * 8;
    int2* pzn      = (int2*)wsb;                         wsb += (size_t)N_NODES * 8;
    int2* prbe     = (int2*)wsb;                         wsb += (size_t)N_NODES * 8;
    int* pnode     = (int*)wsb;                          wsb += (size_t)N_NODES * 4;
    int* bhist     = (int*)wsb;                          wsb += 64 * 64 * 4;
    int* row_ptr   = (int*)wsb;                          wsb += (N_NODES + 4) * 4;
    int* cnt       = (int*)wsb;                          wsb += N_NODES * 4;
    int* fill      = (int*)wsb;                          wsb += N_NODES * 4;
    int* col       = (int*)wsb;                          wsb += N_EDGES * 4;
    int* flags     = (int*)wsb;                          wsb += 128 * 4;

    // ---- prep: all converts/swizzles/zeroing in one dispatch ----
    prep_kernel<<<1146, 256, 0, stream>>>(
        sage_Wself, sage_Wneigh, Wd, Wc, gin_W1, gin_W2, z_table, z, node_id,
        WsT, WnT, WdT, WcT, W12P, zt16, zn2, cnt, flags);

    // ---- projection GEMM (79 blocks) overlapped with edge histogram ----
    proj_hist_kernel<<<79 + N_EDGES / 256, 256, 0, stream>>>(
        d_feat, c_feat, WdT, WcT, projh, dst, cnt);

    // ---- CSR build + degree sort ----
    scan_fused_kernel<<<64, 256, 0, stream>>>(
        cnt, row_ptr, fill, flags, zn2, pzn, prbe, pnode, bhist);
    scatter_kernel<<<N_EDGES / 256, 256, 0, stream>>>(src, dst, zn2, fill, col, colzn);

    // ---- GIN gather (high occupancy) then dense MLP ----
    gather_kernel<<<N_NODES / 16, 256, 0, stream>>>(
        prbe, pzn, colzn, zt16, projh, AGGx);
    gin_mlp_kernel<<<N_NODES / 64, 256, 0, stream>>>(
        AGGx, pnode, W12P, gin_b1, gin_b2, Hh);

    // ---- merged: Ws-half GEMM (1024 blocks) + SAGE aggregation (4096) ----
    agg_wsgemm_kernel<<<1024 + N_NODES / 16, 256, 0, stream>>>(
        prbe, pnode, col, Hh, AGGh, WsT, sage_b, Pf32);

    // ---- H2 = AGG@Wn + P ----
    dim3 ggrid(N_NODES / 128, HID / 128);
    gemm2_kernel<<<ggrid, 256, 0, stream>>>(AGGh, WnT, Pf32, H2h);

    // ---- fused max pool + head ----
    pool_head_kernel<<<N_GRAPHS, 256, 0, stream>>>(
        H2h, graph_ids, lin1_W, lin1_b, lin2_W, lin2_b, out);
}

// Round 8
// 346.511 us; speedup vs baseline: 1.1201x; 1.1201x over previous
//
#include <hip/hip_runtime.h>
#include <hip/hip_bf16.h>

#define N_NODES     65536
#define N_EDGES     524288
#define N_GRAPHS    512
#define G_NODES_N   10000
#define NUM_DIS     2000
#define IN_DIM      128
#define HID         256
#define D_FEAT      512
#define MAX_Z       4000

typedef _Float16 half8 __attribute__((ext_vector_type(8)));
typedef float    f32x4 __attribute__((ext_vector_type(4)));

typedef __attribute__((address_space(1))) const void as1_void;
typedef __attribute__((address_space(3))) void       as3_void;

// ---------------------------------------------------------------------------
// 1. prep + edge histogram in ONE dispatch (cnt/flags pre-zeroed by memset).
//    zn2 stores BYTE offsets (z*256, node_id*256).
// ---------------------------------------------------------------------------
__global__ __launch_bounds__(256) void prep_hist_kernel(
    const float* __restrict__ Ws, const float* __restrict__ Wn,
    const float* __restrict__ Wd, const float* __restrict__ Wc,
    const float* __restrict__ W1, const float* __restrict__ W2,
    const float* __restrict__ z_table,
    const int* __restrict__ z, const int* __restrict__ node_id,
    const int* __restrict__ dst,
    _Float16* __restrict__ WsT, _Float16* __restrict__ WnT,
    _Float16* __restrict__ WdT, _Float16* __restrict__ WcT,
    _Float16* __restrict__ W12P, _Float16* __restrict__ zt16,
    int2* __restrict__ zn2, int* __restrict__ cnt)
{
    const int b = blockIdx.x;
    const int tid = threadIdx.x;
    if (b < 64) {
        __shared__ float tile[64][65];
        const float* W; _Float16* T; int K, N, k0, n0;
        if (b < 32) {
            const int mat = b >> 4, t = b & 15;
            K = HID; N = HID; k0 = (t >> 2) * 64; n0 = (t & 3) * 64;
            W = (mat == 0) ? Ws : Wn;
            T = (mat == 0) ? WsT : WnT;
        } else {
            const int bb = b - 32;
            const int mat = bb >> 4, t = bb & 15;
            K = D_FEAT; N = IN_DIM; k0 = (t >> 1) * 64; n0 = (t & 1) * 64;
            W = (mat == 0) ? Wd : Wc;
            T = (mat == 0) ? WdT : WcT;
        }
        const int tx = tid & 63, ty = tid >> 6;
        #pragma unroll
        for (int r = 0; r < 64; r += 4)
            tile[r + ty][tx] = W[(size_t)(k0 + r + ty) * N + n0 + tx];
        __syncthreads();
        #pragma unroll
        for (int c = 0; c < 64; c += 4)
            T[(size_t)(n0 + c + ty) * K + k0 + tx] = (_Float16)tile[tx][c + ty];
    } else if (b < 576) {
        const int bb = b - 64;              // 0..511
        const int mat = bb >> 8;            // 0: W1, 1: W2
        const int k = bb & 255;
        const int n = tid;
        const float* W = mat ? W2 : W1;
        const float v = W[(size_t)k * HID + n];
        const size_t idx = (size_t)(mat * 8 + (k >> 5)) * 8192
                         + (size_t)((((k >> 3) & 3) * 256 + n) * 8 + (k & 7));
        W12P[idx] = (_Float16)v;
    } else if (b < 826) {
        const size_t base = ((size_t)(b - 576) * 256 + tid) * 8;  // < 512000
        const float4 f0 = *(const float4*)(z_table + base);
        const float4 f1 = *(const float4*)(z_table + base + 4);
        half8 h;
        h[0]=(_Float16)f0.x; h[1]=(_Float16)f0.y; h[2]=(_Float16)f0.z; h[3]=(_Float16)f0.w;
        h[4]=(_Float16)f1.x; h[5]=(_Float16)f1.y; h[6]=(_Float16)f1.z; h[7]=(_Float16)f1.w;
        *(half8*)(zt16 + base) = h;
    } else if (b < 1082) {
        const int i = (b - 826) * 256 + tid;
        zn2[i] = make_int2(z[i] << 8, node_id[i] << 8);   // byte offsets
    } else {
        const int e = (b - 1082) * 256 + tid;             // 2048 blocks, exact
        atomicAdd(&cnt[dst[e]], 1);
    }
}

// ---------------------------------------------------------------------------
// 2. CSR build: fused ALL-PUBLISH scan (flags pre-zeroed by memset).
// ---------------------------------------------------------------------------
__global__ __launch_bounds__(256) void scan_fused_kernel(
    const int* __restrict__ cnt, int* __restrict__ row_ptr,
    int* __restrict__ fill, int* __restrict__ flags)
{
    __shared__ int a[256], b[256];
    __shared__ int sums[64];
    __shared__ int segbase;
    const int t = threadIdx.x;
    const int blk = blockIdx.x;
    const int base = blk * 1024 + t * 4;
    const int4 c = *(const int4*)(cnt + base);
    const int s = c.x + c.y + c.z + c.w;
    a[t] = s;
    __syncthreads();
    int* in = a; int* out = b;
    for (int off = 1; off < 256; off <<= 1) {
        out[t] = in[t] + ((t >= off) ? in[t - off] : 0);
        __syncthreads();
        int* tmp = in; in = out; out = tmp;
    }
    if (t == 0) {
        atomicExch(&flags[64 + blk], in[255]);
        __threadfence();
        atomicAdd(&flags[0], 1);
        while (atomicAdd(&flags[0], 0) < 64) {}
    }
    __syncthreads();
    if (t < 64) sums[t] = atomicAdd(&flags[64 + t], 0);
    __syncthreads();
    if (t == 0) {
        int pfx = 0;
        for (int i = 0; i < blk; ++i) pfx += sums[i];
        segbase = pfx;
        if (blk == 63) {
            int tot = pfx;
            for (int i = blk; i < 64; ++i) tot += sums[i];
            row_ptr[N_NODES] = tot;
        }
    }
    __syncthreads();
    const int run = in[t] - s + segbase;
    int4 r;
    r.x = run; r.y = run + c.x; r.z = r.y + c.y; r.w = r.z + c.z;
    *(int4*)(row_ptr + base) = r;
    *(int4*)(fill + base) = r;
}

// ---------------------------------------------------------------------------
// 3. MERGED: projection GEMM (blocks 0..78) + edge scatter (blocks 79..2126).
//    proj needs only prep's WdT/WcT; it must finish before gather — exactly
//    scatter's window, so its MFMA work hides under scatter's atomics.
// ---------------------------------------------------------------------------
__global__ __launch_bounds__(256) void scatter_proj_kernel(
    const float* __restrict__ dtab, const float* __restrict__ ctab,
    const _Float16* __restrict__ WdT, const _Float16* __restrict__ WcT,
    _Float16* __restrict__ proj,
    const int* __restrict__ src, const int* __restrict__ dst,
    const int2* __restrict__ zn2,
    int* __restrict__ fill, int* __restrict__ col, int2* __restrict__ colzn)
{
    __shared__ _Float16 Alds[128 * 40];
    __shared__ _Float16 Blds[128 * 40];
    const int blk = blockIdx.x;
    if (blk >= 79) {
        const int e = (blk - 79) * 256 + threadIdx.x;
        if (e < N_EDGES) {
            const int s = src[e];
            const int pos = atomicAdd(&fill[dst[e]], 1);
            col[pos] = s;
            colzn[pos] = zn2[s];
        }
        return;
    }
    const float* tab; const _Float16* WT; int base, M, bm;
    if (blk < 16) { tab = dtab; WT = WdT; base = 0;           M = NUM_DIS + 1;             bm = blk * 128; }
    else          { tab = ctab; WT = WcT; base = NUM_DIS + 1; M = G_NODES_N - NUM_DIS - 1; bm = (blk - 16) * 128; }
    const int tid  = threadIdx.x;
    const int wave = tid >> 6, lane = tid & 63;
    const int q    = lane >> 4, l16 = lane & 15;
    const int mbase = (wave & 1) * 64, nbase = (wave >> 1) * 64;
    const int r = tid >> 1, s = tid & 1;

    f32x4 acc[4][4] = {};

    for (int kc = 0; kc < 16; ++kc) {
        const int k0 = kc * 32;
        const int arow = min(bm + r, M - 1);
        const float* gA = tab + (size_t)(base + arow) * D_FEAT + k0 + s * 16;
        const _Float16* gB = WT + (size_t)r * D_FEAT + k0 + s * 16;
        const float4 f0 = ((const float4*)gA)[0];
        const float4 f1 = ((const float4*)gA)[1];
        const float4 f2 = ((const float4*)gA)[2];
        const float4 f3 = ((const float4*)gA)[3];
        const half8 hb0 = *(const half8*)gB;
        const half8 hb1 = *(const half8*)(gB + 8);
        half8 h0, h1;
        h0[0]=(_Float16)f0.x; h0[1]=(_Float16)f0.y; h0[2]=(_Float16)f0.z; h0[3]=(_Float16)f0.w;
        h0[4]=(_Float16)f1.x; h0[5]=(_Float16)f1.y; h0[6]=(_Float16)f1.z; h0[7]=(_Float16)f1.w;
        h1[0]=(_Float16)f2.x; h1[1]=(_Float16)f2.y; h1[2]=(_Float16)f2.z; h1[3]=(_Float16)f2.w;
        h1[4]=(_Float16)f3.x; h1[5]=(_Float16)f3.y; h1[6]=(_Float16)f3.z; h1[7]=(_Float16)f3.w;
        __syncthreads();
        *(half8*)&Alds[r * 40 + s * 16]     = h0;
        *(half8*)&Alds[r * 40 + s * 16 + 8] = h1;
        *(half8*)&Blds[r * 40 + s * 16]     = hb0;
        *(half8*)&Blds[r * 40 + s * 16 + 8] = hb1;
        __syncthreads();
        half8 a[4], b[4];
        #pragma unroll
        for (int i = 0; i < 4; ++i)
            a[i] = *(const half8*)&Alds[(mbase + i * 16 + l16) * 40 + q * 8];
        #pragma unroll
        for (int j = 0; j < 4; ++j)
            b[j] = *(const half8*)&Blds[(nbase + j * 16 + l16) * 40 + q * 8];
        #pragma unroll
        for (int i = 0; i < 4; ++i)
            #pragma unroll
            for (int j = 0; j < 4; ++j)
                acc[i][j] = __builtin_amdgcn_mfma_f32_16x16x32_f16(a[i], b[j], acc[i][j], 0, 0, 0);
    }

    #pragma unroll
    for (int j = 0; j < 4; ++j) {
        const int colg = nbase + j * 16 + l16;   // 0..127
        #pragma unroll
        for (int i = 0; i < 4; ++i) {
            #pragma unroll
            for (int rr = 0; rr < 4; ++rr) {
                const int row = bm + mbase + i * 16 + q * 4 + rr;
                if (row < M)
                    proj[(size_t)(base + row) * IN_DIM + colg] = (_Float16)acc[i][j][rr];
            }
        }
    }
}

// ---------------------------------------------------------------------------
// 4. Fused GIN (R2 shape): 256 threads, M=64, 2-pass gather with idx
//    prefetch (16 loads in flight), reg-prefetch GEMM, H1 stays in LDS.
// ---------------------------------------------------------------------------
__global__ __launch_bounds__(256) void gin_fused_kernel(
    const int* __restrict__ row_ptr, const int2* __restrict__ colzn,
    const int2* __restrict__ zn2,
    const _Float16* __restrict__ zt16, const _Float16* __restrict__ proj,
    const _Float16* __restrict__ W12P,
    const float* __restrict__ b1, const float* __restrict__ b2,
    _Float16* __restrict__ H)
{
    __shared__ _Float16 Apanel[64 * 264];   // 33792 B
    __shared__ _Float16 Blds[8192];         // 16384 B

    const int bm   = blockIdx.x * 64;
    const int tid  = threadIdx.x;
    const int wave = tid >> 6, lane = tid & 63;
    const int q    = lane >> 4, l16 = lane & 15;
    const int nbase = wave * 64;
    const int sb   = wave * 256 + lane;

    // chunk-0 DMA overlaps the gather phase
    #pragma unroll
    for (int tt = 0; tt < 4; ++tt) {
        const int seg = (wave * 4 + tt) * 64 + lane;
        __builtin_amdgcn_global_load_lds((as1_void*)(W12P + seg * 8),
            (as3_void*)&Blds[(wave * 4 + tt) * 64 * 8], 16, 0, 0);
    }

    // ---- phase 0: gather (self + neighbor sum), idx-prefetch pipeline ----
    {
        const int p = tid & 7;              // dim-slice 0..7
        const char* ztb = (const char*)zt16 + p * 32;
        const char* prb = (const char*)proj + p * 32;
        #pragma unroll 1
        for (int pass = 0; pass < 2; ++pass) {
            const int r  = (tid >> 3) + (pass << 5);   // row 0..63
            const int gr = bm + r;
            const int beg = row_ptr[gr], end = row_ptr[gr + 1];
            float za[16], pa[16];
            {
                const int2 zn = zn2[gr];
                const half8* zp = (const half8*)(ztb + zn.x);
                const half8* pp = (const half8*)(prb + zn.y);
                const half8 z0 = zp[0], z1 = zp[1], p0 = pp[0], p1 = pp[1];
                #pragma unroll
                for (int i = 0; i < 8; ++i) {
                    za[i] = (float)z0[i]; za[8 + i] = (float)z1[i];
                    pa[i] = (float)p0[i]; pa[8 + i] = (float)p1[i];
                }
            }
            int e = beg;
            int2 iA, iB, iC, iD;
            if (e + 4 <= end) {
                iA = colzn[e]; iB = colzn[e + 1]; iC = colzn[e + 2]; iD = colzn[e + 3];
            }
            for (; e + 4 <= end; e += 4) {
                const half8* zpA = (const half8*)(ztb + iA.x);
                const half8* ppA = (const half8*)(prb + iA.y);
                const half8* zpB = (const half8*)(ztb + iB.x);
                const half8* ppB = (const half8*)(prb + iB.y);
                const half8* zpC = (const half8*)(ztb + iC.x);
                const half8* ppC = (const half8*)(prb + iC.y);
                const half8* zpD = (const half8*)(ztb + iD.x);
                const half8* ppD = (const half8*)(prb + iD.y);
                const half8 zA0 = zpA[0], zA1 = zpA[1], pA0 = ppA[0], pA1 = ppA[1];
                const half8 zB0 = zpB[0], zB1 = zpB[1], pB0 = ppB[0], pB1 = ppB[1];
                const half8 zC0 = zpC[0], zC1 = zpC[1], pC0 = ppC[0], pC1 = ppC[1];
                const half8 zD0 = zpD[0], zD1 = zpD[1], pD0 = ppD[0], pD1 = ppD[1];
                if (e + 8 <= end) {
                    iA = colzn[e + 4]; iB = colzn[e + 5];
                    iC = colzn[e + 6]; iD = colzn[e + 7];
                }
                #pragma unroll
                for (int i = 0; i < 8; ++i) {
                    za[i]     += ((float)zA0[i] + (float)zB0[i]) + ((float)zC0[i] + (float)zD0[i]);
                    za[8 + i] += ((float)zA1[i] + (float)zB1[i]) + ((float)zC1[i] + (float)zD1[i]);
                    pa[i]     += ((float)pA0[i] + (float)pB0[i]) + ((float)pC0[i] + (float)pD0[i]);
                    pa[8 + i] += ((float)pA1[i] + (float)pB1[i]) + ((float)pC1[i] + (float)pD1[i]);
                }
            }
            for (; e + 2 <= end; e += 2) {
                const int2 jA = colzn[e];
                const int2 jB = colzn[e + 1];
                const half8* zpA = (const half8*)(ztb + jA.x);
                const half8* ppA = (const half8*)(prb + jA.y);
                const half8* zpB = (const half8*)(ztb + jB.x);
                const half8* ppB = (const half8*)(prb + jB.y);
                const half8 zA0 = zpA[0], zA1 = zpA[1], pA0 = ppA[0], pA1 = ppA[1];
                const half8 zB0 = zpB[0], zB1 = zpB[1], pB0 = ppB[0], pB1 = ppB[1];
                #pragma unroll
                for (int i = 0; i < 8; ++i) {
                    za[i]     += (float)zA0[i] + (float)zB0[i];
                    za[8 + i] += (float)zA1[i] + (float)zB1[i];
                    pa[i]     += (float)pA0[i] + (float)pB0[i];
                    pa[8 + i] += (float)pA1[i] + (float)pB1[i];
                }
            }
            if (e < end) {
                const int2 jA = colzn[e];
                const half8* zp = (const half8*)(ztb + jA.x);
                const half8* pp = (const half8*)(prb + jA.y);
                const half8 z0 = zp[0], z1 = zp[1], p0 = pp[0], p1 = pp[1];
                #pragma unroll
                for (int i = 0; i < 8; ++i) {
                    za[i] += (float)z0[i]; za[8 + i] += (float)z1[i];
                    pa[i] += (float)p0[i]; pa[8 + i] += (float)p1[i];
                }
            }
            half8 oz0, oz1, op0, op1;
            #pragma unroll
            for (int i = 0; i < 8; ++i) {
                oz0[i] = (_Float16)za[i];     oz1[i] = (_Float16)za[8 + i];
                op0[i] = (_Float16)pa[i];     op1[i] = (_Float16)pa[8 + i];
            }
            *(half8*)&Apanel[r * 264 + p * 16]           = oz0;
            *(half8*)&Apanel[r * 264 + p * 16 + 8]       = oz1;
            *(half8*)&Apanel[r * 264 + 128 + p * 16]     = op0;
            *(half8*)&Apanel[r * 264 + 128 + p * 16 + 8] = op1;
        }
    }
    __syncthreads();   // gather visible + chunk-0 DMA drained

    // ---- GEMM phase: reg-prefetch pipeline, single Blds buffer ----
    half8 pf0, pf1, pf2, pf3;
    auto pfetch = [&](int c) {
        const _Float16* s = W12P + (size_t)c * 8192 + (size_t)sb * 8;
        pf0 = *(const half8*)(s);
        pf1 = *(const half8*)(s + 512);
        pf2 = *(const half8*)(s + 1024);
        pf3 = *(const half8*)(s + 1536);
    };
    pfetch(1);

    f32x4 acc[4][4] = {};
    for (int c = 0; c < 16; ++c) {
        const int kl = (c & 7) * 32;
        half8 a[4], b[4];
        #pragma unroll
        for (int i = 0; i < 4; ++i)
            a[i] = *(const half8*)&Apanel[(i * 16 + l16) * 264 + kl + q * 8];
        #pragma unroll
        for (int j = 0; j < 4; ++j)
            b[j] = *(const half8*)&Blds[(q * 256 + nbase + j * 16 + l16) * 8];
        #pragma unroll
        for (int i = 0; i < 4; ++i)
            #pragma unroll
            for (int j = 0; j < 4; ++j)
                acc[i][j] = __builtin_amdgcn_mfma_f32_16x16x32_f16(a[i], b[j], acc[i][j], 0, 0, 0);
        if (c == 15) break;
        __syncthreads();                    // all waves done reading chunk c
        *(half8*)&Blds[sb * 8]         = pf0;   // write chunk c+1
        *(half8*)&Blds[(sb + 64) * 8]  = pf1;
        *(half8*)&Blds[(sb + 128) * 8] = pf2;
        *(half8*)&Blds[(sb + 192) * 8] = pf3;
        if (c == 7) {
            // H1 = relu(X@W1 + b1) writeback (Apanel readers past barrier)
            #pragma unroll
            for (int j = 0; j < 4; ++j) {
                const int colg = nbase + j * 16 + l16;
                const float bv = b1[colg];
                #pragma unroll
                for (int i = 0; i < 4; ++i)
                    #pragma unroll
                    for (int rr = 0; rr < 4; ++rr) {
                        const float v = fmaxf(acc[i][j][rr] + bv, 0.0f);
                        Apanel[(i * 16 + q * 4 + rr) * 264 + colg] = (_Float16)v;
                        acc[i][j][rr] = 0.0f;
                    }
            }
        }
        if (c < 14) pfetch(c + 2);          // loads fly over next MFMA
        __syncthreads();                    // chunk c+1 / Apanel visible
    }

    #pragma unroll
    for (int j = 0; j < 4; ++j) {
        const int colg = nbase + j * 16 + l16;
        const float bv = b2[colg];
        #pragma unroll
        for (int i = 0; i < 4; ++i)
            #pragma unroll
            for (int rr = 0; rr < 4; ++rr) {
                const int rowg = bm + i * 16 + q * 4 + rr;
                H[(size_t)rowg * HID + colg] = (_Float16)(acc[i][j][rr] + bv);
            }
    }
}

// ---------------------------------------------------------------------------
// 5. CSR gather-aggregation (SAGE mean): 32 lanes/row, 8-edge unroll.
// ---------------------------------------------------------------------------
__global__ __launch_bounds__(256) void csr_agg_kernel(
    const int* __restrict__ row_ptr, const int* __restrict__ col,
    const _Float16* __restrict__ F, _Float16* __restrict__ OUT)
{
    const int t = blockIdx.x * 256 + threadIdx.x;
    const int d = t >> 5;
    const int q = t & 31;
    const int beg = row_ptr[d];
    const int end = row_ptr[d + 1];
    float acc[8] = {0.f,0.f,0.f,0.f,0.f,0.f,0.f,0.f};
    int e = beg;
    for (; e + 8 <= end; e += 8) {
        const int s0 = col[e],     s1 = col[e + 1];
        const int s2 = col[e + 2], s3 = col[e + 3];
        const int s4 = col[e + 4], s5 = col[e + 5];
        const int s6 = col[e + 6], s7 = col[e + 7];
        const half8 v0 = *(const half8*)(F + (size_t)s0 * HID + q * 8);
        const half8 v1 = *(const half8*)(F + (size_t)s1 * HID + q * 8);
        const half8 v2 = *(const half8*)(F + (size_t)s2 * HID + q * 8);
        const half8 v3 = *(const half8*)(F + (size_t)s3 * HID + q * 8);
        const half8 v4 = *(const half8*)(F + (size_t)s4 * HID + q * 8);
        const half8 v5 = *(const half8*)(F + (size_t)s5 * HID + q * 8);
        const half8 v6 = *(const half8*)(F + (size_t)s6 * HID + q * 8);
        const half8 v7 = *(const half8*)(F + (size_t)s7 * HID + q * 8);
        #pragma unroll
        for (int i = 0; i < 8; ++i)
            acc[i] += (((float)v0[i] + (float)v1[i]) + ((float)v2[i] + (float)v3[i]))
                    + (((float)v4[i] + (float)v5[i]) + ((float)v6[i] + (float)v7[i]));
    }
    for (; e + 4 <= end; e += 4) {
        const int s0 = col[e],     s1 = col[e + 1];
        const int s2 = col[e + 2], s3 = col[e + 3];
        const half8 v0 = *(const half8*)(F + (size_t)s0 * HID + q * 8);
        const half8 v1 = *(const half8*)(F + (size_t)s1 * HID + q * 8);
        const half8 v2 = *(const half8*)(F + (size_t)s2 * HID + q * 8);
        const half8 v3 = *(const half8*)(F + (size_t)s3 * HID + q * 8);
        #pragma unroll
        for (int i = 0; i < 8; ++i)
            acc[i] += ((float)v0[i] + (float)v1[i]) + ((float)v2[i] + (float)v3[i]);
    }
    for (; e < end; ++e) {
        const half8 v0 = *(const half8*)(F + (size_t)col[e] * HID + q * 8);
        #pragma unroll
        for (int i = 0; i < 8; ++i) acc[i] += (float)v0[i];
    }
    const float rs = 1.0f / fmaxf((float)(end - beg), 1.0f);
    half8 o;
    #pragma unroll
    for (int i = 0; i < 8; ++i) o[i] = (_Float16)(acc[i] * rs);
    *(half8*)(OUT + (size_t)d * HID + q * 8) = o;
}

// ---------------------------------------------------------------------------
// 6. MFMA f16 GEMM (SAGE): C = [A1|A2] @ [B1;B2] + bias, K=512 -> f16.
// ---------------------------------------------------------------------------
__global__ __launch_bounds__(256) void mfma_gemm_kernel(
    const _Float16* __restrict__ A1, const _Float16* __restrict__ A2,
    const _Float16* __restrict__ B1T, const _Float16* __restrict__ B2T,
    const float* __restrict__ bias, _Float16* __restrict__ Ch)
{
    __shared__ _Float16 Alds[128 * 32];
    __shared__ _Float16 Blds[128 * 32];
    const int bm   = blockIdx.x * 128;
    const int bn   = blockIdx.y * 128;
    const int tid  = threadIdx.x;
    const int wave = tid >> 6, lane = tid & 63;
    const int q    = lane >> 4, l16 = lane & 15;
    const int mbase = (wave & 1) * 64, nbase = (wave >> 1) * 64;

    const int i0 = wave * 128 + lane;
    const int i1 = i0 + 64;
    const int r0 = i0 >> 2, s0 = i0 & 3;
    const int r1 = i1 >> 2, s1 = i1 & 3;

    half8 pa0, pa1, pb0, pb1;
    auto pfetch = [&](int kc) {
        const int k0 = (kc & 7) * 32;
        const _Float16* Ab = (kc < 8) ? A1 : A2;
        const _Float16* Bb = (kc < 8) ? B1T : B2T;
        pa0 = *(const half8*)(Ab + (size_t)(bm + r0) * HID + k0 + s0 * 8);
        pa1 = *(const half8*)(Ab + (size_t)(bm + r1) * HID + k0 + s1 * 8);
        pb0 = *(const half8*)(Bb + (size_t)(bn + r0) * HID + k0 + s0 * 8);
        pb1 = *(const half8*)(Bb + (size_t)(bn + r1) * HID + k0 + s1 * 8);
    };
    pfetch(0);

    f32x4 acc[4][4] = {};

    for (int kc = 0; kc < 16; ++kc) {
        __syncthreads();
        *(half8*)&Alds[i0 * 8] = pa0;
        *(half8*)&Alds[i1 * 8] = pa1;
        *(half8*)&Blds[i0 * 8] = pb0;
        *(half8*)&Blds[i1 * 8] = pb1;
        if (kc < 15) pfetch(kc + 1);
        __syncthreads();
        half8 a[4], b[4];
        #pragma unroll
        for (int i = 0; i < 4; ++i)
            a[i] = *(const half8*)&Alds[(mbase + i * 16 + l16) * 32 + q * 8];
        #pragma unroll
        for (int j = 0; j < 4; ++j)
            b[j] = *(const half8*)&Blds[(nbase + j * 16 + l16) * 32 + q * 8];
        #pragma unroll
        for (int i = 0; i < 4; ++i)
            #pragma unroll
            for (int j = 0; j < 4; ++j)
                acc[i][j] = __builtin_amdgcn_mfma_f32_16x16x32_f16(a[i], b[j], acc[i][j], 0, 0, 0);
    }

    #pragma unroll
    for (int j = 0; j < 4; ++j) {
        const int colg = bn + nbase + j * 16 + l16;
        const float bv = bias[colg];
        #pragma unroll
        for (int i = 0; i < 4; ++i) {
            #pragma unroll
            for (int rr = 0; rr < 4; ++rr) {
                const int rowg = bm + mbase + i * 16 + q * 4 + rr;
                Ch[(size_t)rowg * HID + colg] = (_Float16)(acc[i][j][rr] + bv);
            }
        }
    }
}

// ---------------------------------------------------------------------------
// 7. Fused max-pool + head MLP: one block per graph.
// ---------------------------------------------------------------------------
__global__ __launch_bounds__(256) void pool_head_kernel(
    const _Float16* __restrict__ H2, const int* __restrict__ gid,
    const float* __restrict__ W1, const float* __restrict__ b1,
    const float* __restrict__ W2, const float* __restrict__ b2,
    float* __restrict__ out)
{
    const int g = blockIdx.x;
    const int tid = threadIdx.x;
    int lo = 0, hi = N_NODES;
    while (lo < hi) { const int mid = (lo + hi) >> 1; if (gid[mid] < g) lo = mid + 1; else hi = mid; }
    const int start = lo;
    hi = N_NODES;
    while (lo < hi) { const int mid = (lo + hi) >> 1; if (gid[mid] < g + 1) lo = mid + 1; else hi = mid; }
    const int end = lo;

    const int rowofs = tid >> 5;        // 0..7
    const int q = tid & 31;             // half8 col slice
    float m8[8];
    #pragma unroll
    for (int k = 0; k < 8; ++k) m8[k] = -INFINITY;
    for (int i = start + rowofs; i < end; i += 8) {
        const half8 v = *(const half8*)(H2 + (size_t)i * HID + q * 8);
        #pragma unroll
        for (int k = 0; k < 8; ++k) m8[k] = fmaxf(m8[k], (float)v[k]);
    }
    __shared__ float part[8][256];
    #pragma unroll
    for (int k = 0; k < 8; ++k) part[rowofs][q * 8 + k] = m8[k];
    __syncthreads();
    __shared__ float row[HID];
    __shared__ float red[HID];
    const int j = tid;
    float m = part[0][j];
    #pragma unroll
    for (int r = 1; r < 8; ++r) m = fmaxf(m, part[r][j]);
    row[j] = (m == -INFINITY) ? 0.0f : m;
    __syncthreads();
    float acc = b1[j];
    #pragma unroll 8
    for (int k = 0; k < HID; ++k)
        acc = fmaf(row[k], W1[k * HID + j], acc);
    acc = fmaxf(acc, 0.f);
    red[j] = acc * W2[j];
    __syncthreads();
    for (int s = 128; s > 0; s >>= 1) {
        if (j < s) red[j] += red[j + s];
        __syncthreads();
    }
    if (j == 0) out[g] = red[0] + b2[0];
}

// ---------------------------------------------------------------------------
extern "C" void kernel_launch(void* const* d_in, const int* in_sizes, int n_in,
                              void* d_out, int out_size, void* d_ws, size_t ws_size,
                              hipStream_t stream)
{
    const int*   z         = (const int*)d_in[0];
    const int*   node_id   = (const int*)d_in[1];
    const int*   src       = (const int*)d_in[2];
    const int*   dst       = (const int*)d_in[3];
    const int*   graph_ids = (const int*)d_in[4];
    const float* z_table   = (const float*)d_in[5];
    const float* d_feat    = (const float*)d_in[6];
    const float* c_feat    = (const float*)d_in[7];
    const float* Wd        = (const float*)d_in[8];
    const float* Wc        = (const float*)d_in[9];
    const float* gin_W1    = (const float*)d_in[10];
    const float* gin_b1    = (const float*)d_in[11];
    const float* gin_W2    = (const float*)d_in[12];
    const float* gin_b2    = (const float*)d_in[13];
    const float* sage_Wself  = (const float*)d_in[14];
    const float* sage_Wneigh = (const float*)d_in[15];
    const float* sage_b    = (const float*)d_in[16];
    const float* lin1_W    = (const float*)d_in[17];
    const float* lin1_b    = (const float*)d_in[18];
    const float* lin2_W    = (const float*)d_in[19];
    const float* lin2_b    = (const float*)d_in[20];
    float* out = (float*)d_out;

    // ---- workspace carve-up ----
    const size_t NH = (size_t)N_NODES * HID;
    char* wsb = (char*)d_ws;
    _Float16* Hh   = (_Float16*)wsb;                     wsb += NH * 2;
    _Float16* AGGh = (_Float16*)wsb;                     wsb += NH * 2;
    _Float16* H2h  = (_Float16*)wsb;                     wsb += NH * 2;
    _Float16* projh= (_Float16*)wsb;                     wsb += (size_t)G_NODES_N * IN_DIM * 2;
    _Float16* W12P = (_Float16*)wsb;                     wsb += 16 * 8192 * 2;
    _Float16* WsT  = (_Float16*)wsb;                     wsb += HID * HID * 2;
    _Float16* WnT  = (_Float16*)wsb;                     wsb += HID * HID * 2;
    _Float16* WdT  = (_Float16*)wsb;                     wsb += D_FEAT * IN_DIM * 2;
    _Float16* WcT  = (_Float16*)wsb;                     wsb += D_FEAT * IN_DIM * 2;
    _Float16* zt16 = (_Float16*)wsb;                     wsb += (size_t)MAX_Z * IN_DIM * 2;
    int2* zn2      = (int2*)wsb;                         wsb += (size_t)N_NODES * 8;
    int2* colzn    = (int2*)wsb;                         wsb += (size_t)(N_EDGES + 8) * 8;
    int* row_ptr   = (int*)wsb;                          wsb += (N_NODES + 4) * 4;
    int* cnt       = (int*)wsb;                          wsb += N_NODES * 4;
    int* fill      = (int*)wsb;                          wsb += N_NODES * 4;
    int* col       = (int*)wsb;                          wsb += N_EDGES * 4;
    int* flags     = (int*)wsb;                          wsb += 128 * 4;

    // ---- zero cnt/flags (graph-capturable), then prep + histogram ----
    hipMemsetAsync(cnt, 0, N_NODES * sizeof(int), stream);
    hipMemsetAsync(flags, 0, 128 * sizeof(int), stream);
    prep_hist_kernel<<<1082 + N_EDGES / 256, 256, 0, stream>>>(
        sage_Wself, sage_Wneigh, Wd, Wc, gin_W1, gin_W2, z_table, z, node_id,
        dst, WsT, WnT, WdT, WcT, W12P, zt16, zn2, cnt);

    // ---- CSR scan ----
    scan_fused_kernel<<<64, 256, 0, stream>>>(cnt, row_ptr, fill, flags);

    // ---- scatter (2048 blocks) + projection GEMM (79 blocks) merged ----
    scatter_proj_kernel<<<79 + N_EDGES / 256, 256, 0, stream>>>(
        d_feat, c_feat, WdT, WcT, projh, src, dst, zn2, fill, col, colzn);

    // ---- fused GIN: gather + MLP, H1 stays in LDS (M=64 rows/block) ----
    gin_fused_kernel<<<N_NODES / 64, 256, 0, stream>>>(
        row_ptr, colzn, zn2, zt16, projh, W12P, gin_b1, gin_b2, Hh);

    // ---- SAGE mean aggregation ----
    csr_agg_kernel<<<(N_NODES * 32) / 256, 256, 0, stream>>>(row_ptr, col, Hh, AGGh);

    // ---- SAGE: H2 = H@Wself + AGG@Wneigh + b  (K=512) ----
    dim3 ggrid(N_NODES / 128, HID / 128);
    mfma_gemm_kernel<<<ggrid, 256, 0, stream>>>(Hh, AGGh, WsT, WnT, sage_b, H2h);

    // ---- fused max pool + head ----
    pool_head_kernel<<<N_GRAPHS, 256, 0, stream>>>(
        H2h, graph_ids, lin1_W, lin1_b, lin2_W, lin2_b, out);
}

// Round 10
// 343.631 us; speedup vs baseline: 1.1295x; 1.0084x over previous
//
#include <hip/hip_runtime.h>
#include <hip/hip_bf16.h>

#define N_NODES     65536
#define N_EDGES     524288
#define N_GRAPHS    512
#define G_NODES_N   10000
#define NUM_DIS     2000
#define IN_DIM      128
#define HID         256
#define D_FEAT      512
#define MAX_Z       4000

typedef _Float16 half8 __attribute__((ext_vector_type(8)));
typedef float    f32x4 __attribute__((ext_vector_type(4)));

typedef __attribute__((address_space(1))) const void as1_void;
typedef __attribute__((address_space(3))) void       as3_void;

// ---------------------------------------------------------------------------
// 1. prep + edge histogram in ONE dispatch (cnt/flags pre-zeroed by memset).
//    zn2 stores BYTE offsets (z*256, node_id*256).
// ---------------------------------------------------------------------------
__global__ __launch_bounds__(256) void prep_hist_kernel(
    const float* __restrict__ Ws, const float* __restrict__ Wn,
    const float* __restrict__ Wd, const float* __restrict__ Wc,
    const float* __restrict__ W1, const float* __restrict__ W2,
    const float* __restrict__ z_table,
    const int* __restrict__ z, const int* __restrict__ node_id,
    const int* __restrict__ dst,
    _Float16* __restrict__ WsT, _Float16* __restrict__ WnT,
    _Float16* __restrict__ WdT, _Float16* __restrict__ WcT,
    _Float16* __restrict__ W12P, _Float16* __restrict__ zt16,
    int2* __restrict__ zn2, int* __restrict__ cnt)
{
    const int b = blockIdx.x;
    const int tid = threadIdx.x;
    if (b < 64) {
        __shared__ float tile[64][65];
        const float* W; _Float16* T; int K, N, k0, n0;
        if (b < 32) {
            const int mat = b >> 4, t = b & 15;
            K = HID; N = HID; k0 = (t >> 2) * 64; n0 = (t & 3) * 64;
            W = (mat == 0) ? Ws : Wn;
            T = (mat == 0) ? WsT : WnT;
        } else {
            const int bb = b - 32;
            const int mat = bb >> 4, t = bb & 15;
            K = D_FEAT; N = IN_DIM; k0 = (t >> 1) * 64; n0 = (t & 1) * 64;
            W = (mat == 0) ? Wd : Wc;
            T = (mat == 0) ? WdT : WcT;
        }
        const int tx = tid & 63, ty = tid >> 6;
        #pragma unroll
        for (int r = 0; r < 64; r += 4)
            tile[r + ty][tx] = W[(size_t)(k0 + r + ty) * N + n0 + tx];
        __syncthreads();
        #pragma unroll
        for (int c = 0; c < 64; c += 4)
            T[(size_t)(n0 + c + ty) * K + k0 + tx] = (_Float16)tile[tx][c + ty];
    } else if (b < 576) {
        const int bb = b - 64;              // 0..511
        const int mat = bb >> 8;            // 0: W1, 1: W2
        const int k = bb & 255;
        const int n = tid;
        const float* W = mat ? W2 : W1;
        const float v = W[(size_t)k * HID + n];
        const size_t idx = (size_t)(mat * 8 + (k >> 5)) * 8192
                         + (size_t)((((k >> 3) & 3) * 256 + n) * 8 + (k & 7));
        W12P[idx] = (_Float16)v;
    } else if (b < 826) {
        const size_t base = ((size_t)(b - 576) * 256 + tid) * 8;  // < 512000
        const float4 f0 = *(const float4*)(z_table + base);
        const float4 f1 = *(const float4*)(z_table + base + 4);
        half8 h;
        h[0]=(_Float16)f0.x; h[1]=(_Float16)f0.y; h[2]=(_Float16)f0.z; h[3]=(_Float16)f0.w;
        h[4]=(_Float16)f1.x; h[5]=(_Float16)f1.y; h[6]=(_Float16)f1.z; h[7]=(_Float16)f1.w;
        *(half8*)(zt16 + base) = h;
    } else if (b < 1082) {
        const int i = (b - 826) * 256 + tid;
        zn2[i] = make_int2(z[i] << 8, node_id[i] << 8);   // byte offsets
    } else {
        const int e = (b - 1082) * 256 + tid;             // 2048 blocks, exact
        atomicAdd(&cnt[dst[e]], 1);
    }
}

// ---------------------------------------------------------------------------
// 2. CSR build: fused ALL-PUBLISH scan (flags pre-zeroed by memset).
// ---------------------------------------------------------------------------
__global__ __launch_bounds__(256) void scan_fused_kernel(
    const int* __restrict__ cnt, int* __restrict__ row_ptr,
    int* __restrict__ fill, int* __restrict__ flags)
{
    __shared__ int a[256], b[256];
    __shared__ int sums[64];
    __shared__ int segbase;
    const int t = threadIdx.x;
    const int blk = blockIdx.x;
    const int base = blk * 1024 + t * 4;
    const int4 c = *(const int4*)(cnt + base);
    const int s = c.x + c.y + c.z + c.w;
    a[t] = s;
    __syncthreads();
    int* in = a; int* out = b;
    for (int off = 1; off < 256; off <<= 1) {
        out[t] = in[t] + ((t >= off) ? in[t - off] : 0);
        __syncthreads();
        int* tmp = in; in = out; out = tmp;
    }
    if (t == 0) {
        atomicExch(&flags[64 + blk], in[255]);
        __threadfence();
        atomicAdd(&flags[0], 1);
        while (atomicAdd(&flags[0], 0) < 64) {}
    }
    __syncthreads();
    if (t < 64) sums[t] = atomicAdd(&flags[64 + t], 0);
    __syncthreads();
    if (t == 0) {
        int pfx = 0;
        for (int i = 0; i < blk; ++i) pfx += sums[i];
        segbase = pfx;
        if (blk == 63) {
            int tot = pfx;
            for (int i = blk; i < 64; ++i) tot += sums[i];
            row_ptr[N_NODES] = tot;
        }
    }
    __syncthreads();
    const int run = in[t] - s + segbase;
    int4 r;
    r.x = run; r.y = run + c.x; r.z = r.y + c.y; r.w = r.z + c.z;
    *(int4*)(row_ptr + base) = r;
    *(int4*)(fill + base) = r;
}

// ---------------------------------------------------------------------------
// 3. MERGED: projection GEMM (blocks 0..78) + edge scatter (blocks 79..2126).
// ---------------------------------------------------------------------------
__global__ __launch_bounds__(256) void scatter_proj_kernel(
    const float* __restrict__ dtab, const float* __restrict__ ctab,
    const _Float16* __restrict__ WdT, const _Float16* __restrict__ WcT,
    _Float16* __restrict__ proj,
    const int* __restrict__ src, const int* __restrict__ dst,
    const int2* __restrict__ zn2,
    int* __restrict__ fill, int* __restrict__ col, int2* __restrict__ colzn)
{
    __shared__ _Float16 Alds[128 * 40];
    __shared__ _Float16 Blds[128 * 40];
    const int blk = blockIdx.x;
    if (blk >= 79) {
        const int e = (blk - 79) * 256 + threadIdx.x;
        if (e < N_EDGES) {
            const int s = src[e];
            const int pos = atomicAdd(&fill[dst[e]], 1);
            col[pos] = s;
            colzn[pos] = zn2[s];
        }
        return;
    }
    const float* tab; const _Float16* WT; int base, M, bm;
    if (blk < 16) { tab = dtab; WT = WdT; base = 0;           M = NUM_DIS + 1;             bm = blk * 128; }
    else          { tab = ctab; WT = WcT; base = NUM_DIS + 1; M = G_NODES_N - NUM_DIS - 1; bm = (blk - 16) * 128; }
    const int tid  = threadIdx.x;
    const int wave = tid >> 6, lane = tid & 63;
    const int q    = lane >> 4, l16 = lane & 15;
    const int mbase = (wave & 1) * 64, nbase = (wave >> 1) * 64;
    const int r = tid >> 1, s = tid & 1;

    f32x4 acc[4][4] = {};

    for (int kc = 0; kc < 16; ++kc) {
        const int k0 = kc * 32;
        const int arow = min(bm + r, M - 1);
        const float* gA = tab + (size_t)(base + arow) * D_FEAT + k0 + s * 16;
        const _Float16* gB = WT + (size_t)r * D_FEAT + k0 + s * 16;
        const float4 f0 = ((const float4*)gA)[0];
        const float4 f1 = ((const float4*)gA)[1];
        const float4 f2 = ((const float4*)gA)[2];
        const float4 f3 = ((const float4*)gA)[3];
        const half8 hb0 = *(const half8*)gB;
        const half8 hb1 = *(const half8*)(gB + 8);
        half8 h0, h1;
        h0[0]=(_Float16)f0.x; h0[1]=(_Float16)f0.y; h0[2]=(_Float16)f0.z; h0[3]=(_Float16)f0.w;
        h0[4]=(_Float16)f1.x; h0[5]=(_Float16)f1.y; h0[6]=(_Float16)f1.z; h0[7]=(_Float16)f1.w;
        h1[0]=(_Float16)f2.x; h1[1]=(_Float16)f2.y; h1[2]=(_Float16)f2.z; h1[3]=(_Float16)f2.w;
        h1[4]=(_Float16)f3.x; h1[5]=(_Float16)f3.y; h1[6]=(_Float16)f3.z; h1[7]=(_Float16)f3.w;
        __syncthreads();
        *(half8*)&Alds[r * 40 + s * 16]     = h0;
        *(half8*)&Alds[r * 40 + s * 16 + 8] = h1;
        *(half8*)&Blds[r * 40 + s * 16]     = hb0;
        *(half8*)&Blds[r * 40 + s * 16 + 8] = hb1;
        __syncthreads();
        half8 a[4], b[4];
        #pragma unroll
        for (int i = 0; i < 4; ++i)
            a[i] = *(const half8*)&Alds[(mbase + i * 16 + l16) * 40 + q * 8];
        #pragma unroll
        for (int j = 0; j < 4; ++j)
            b[j] = *(const half8*)&Blds[(nbase + j * 16 + l16) * 40 + q * 8];
        #pragma unroll
        for (int i = 0; i < 4; ++i)
            #pragma unroll
            for (int j = 0; j < 4; ++j)
                acc[i][j] = __builtin_amdgcn_mfma_f32_16x16x32_f16(a[i], b[j], acc[i][j], 0, 0, 0);
    }

    #pragma unroll
    for (int j = 0; j < 4; ++j) {
        const int colg = nbase + j * 16 + l16;   // 0..127
        #pragma unroll
        for (int i = 0; i < 4; ++i) {
            #pragma unroll
            for (int rr = 0; rr < 4; ++rr) {
                const int row = bm + mbase + i * 16 + q * 4 + rr;
                if (row < M)
                    proj[(size_t)(base + row) * IN_DIM + colg] = (_Float16)acc[i][j][rr];
            }
        }
    }
}

// ---------------------------------------------------------------------------
// 4. Fused GIN (R2 shape): 256 threads, M=64, 2-pass gather with idx
//    prefetch (16 loads in flight), reg-prefetch GEMM, H1 stays in LDS.
// ---------------------------------------------------------------------------
__global__ __launch_bounds__(256) void gin_fused_kernel(
    const int* __restrict__ row_ptr, const int2* __restrict__ colzn,
    const int2* __restrict__ zn2,
    const _Float16* __restrict__ zt16, const _Float16* __restrict__ proj,
    const _Float16* __restrict__ W12P,
    const float* __restrict__ b1, const float* __restrict__ b2,
    _Float16* __restrict__ H)
{
    __shared__ _Float16 Apanel[64 * 264];   // 33792 B
    __shared__ _Float16 Blds[8192];         // 16384 B

    const int bm   = blockIdx.x * 64;
    const int tid  = threadIdx.x;
    const int wave = tid >> 6, lane = tid & 63;
    const int q    = lane >> 4, l16 = lane & 15;
    const int nbase = wave * 64;
    const int sb   = wave * 256 + lane;

    // chunk-0 DMA overlaps the gather phase
    #pragma unroll
    for (int tt = 0; tt < 4; ++tt) {
        const int seg = (wave * 4 + tt) * 64 + lane;
        __builtin_amdgcn_global_load_lds((as1_void*)(W12P + seg * 8),
            (as3_void*)&Blds[(wave * 4 + tt) * 64 * 8], 16, 0, 0);
    }

    // ---- phase 0: gather (self + neighbor sum), idx-prefetch pipeline ----
    {
        const int p = tid & 7;              // dim-slice 0..7
        const char* ztb = (const char*)zt16 + p * 32;
        const char* prb = (const char*)proj + p * 32;
        #pragma unroll 1
        for (int pass = 0; pass < 2; ++pass) {
            const int r  = (tid >> 3) + (pass << 5);   // row 0..63
            const int gr = bm + r;
            const int beg = row_ptr[gr], end = row_ptr[gr + 1];
            float za[16], pa[16];
            {
                const int2 zn = zn2[gr];
                const half8* zp = (const half8*)(ztb + zn.x);
                const half8* pp = (const half8*)(prb + zn.y);
                const half8 z0 = zp[0], z1 = zp[1], p0 = pp[0], p1 = pp[1];
                #pragma unroll
                for (int i = 0; i < 8; ++i) {
                    za[i] = (float)z0[i]; za[8 + i] = (float)z1[i];
                    pa[i] = (float)p0[i]; pa[8 + i] = (float)p1[i];
                }
            }
            int e = beg;
            int2 iA, iB, iC, iD;
            if (e + 4 <= end) {
                iA = colzn[e]; iB = colzn[e + 1]; iC = colzn[e + 2]; iD = colzn[e + 3];
            }
            for (; e + 4 <= end; e += 4) {
                const half8* zpA = (const half8*)(ztb + iA.x);
                const half8* ppA = (const half8*)(prb + iA.y);
                const half8* zpB = (const half8*)(ztb + iB.x);
                const half8* ppB = (const half8*)(prb + iB.y);
                const half8* zpC = (const half8*)(ztb + iC.x);
                const half8* ppC = (const half8*)(prb + iC.y);
                const half8* zpD = (const half8*)(ztb + iD.x);
                const half8* ppD = (const half8*)(prb + iD.y);
                const half8 zA0 = zpA[0], zA1 = zpA[1], pA0 = ppA[0], pA1 = ppA[1];
                const half8 zB0 = zpB[0], zB1 = zpB[1], pB0 = ppB[0], pB1 = ppB[1];
                const half8 zC0 = zpC[0], zC1 = zpC[1], pC0 = ppC[0], pC1 = ppC[1];
                const half8 zD0 = zpD[0], zD1 = zpD[1], pD0 = ppD[0], pD1 = ppD[1];
                if (e + 8 <= end) {
                    iA = colzn[e + 4]; iB = colzn[e + 5];
                    iC = colzn[e + 6]; iD = colzn[e + 7];
                }
                #pragma unroll
                for (int i = 0; i < 8; ++i) {
                    za[i]     += ((float)zA0[i] + (float)zB0[i]) + ((float)zC0[i] + (float)zD0[i]);
                    za[8 + i] += ((float)zA1[i] + (float)zB1[i]) + ((float)zC1[i] + (float)zD1[i]);
                    pa[i]     += ((float)pA0[i] + (float)pB0[i]) + ((float)pC0[i] + (float)pD0[i]);
                    pa[8 + i] += ((float)pA1[i] + (float)pB1[i]) + ((float)pC1[i] + (float)pD1[i]);
                }
            }
            for (; e + 2 <= end; e += 2) {
                const int2 jA = colzn[e];
                const int2 jB = colzn[e + 1];
                const half8* zpA = (const half8*)(ztb + jA.x);
                const half8* ppA = (const half8*)(prb + jA.y);
                const half8* zpB = (const half8*)(ztb + jB.x);
                const half8* ppB = (const half8*)(prb + jB.y);
                const half8 zA0 = zpA[0], zA1 = zpA[1], pA0 = ppA[0], pA1 = ppA[1];
                const half8 zB0 = zpB[0], zB1 = zpB[1], pB0 = ppB[0], pB1 = ppB[1];
                #pragma unroll
                for (int i = 0; i < 8; ++i) {
                    za[i]     += (float)zA0[i] + (float)zB0[i];
                    za[8 + i] += (float)zA1[i] + (float)zB1[i];
                    pa[i]     += (float)pA0[i] + (float)pB0[i];
                    pa[8 + i] += (float)pA1[i] + (float)pB1[i];
                }
            }
            if (e < end) {
                const int2 jA = colzn[e];
                const half8* zp = (const half8*)(ztb + jA.x);
                const half8* pp = (const half8*)(prb + jA.y);
                const half8 z0 = zp[0], z1 = zp[1], p0 = pp[0], p1 = pp[1];
                #pragma unroll
                for (int i = 0; i < 8; ++i) {
                    za[i] += (float)z0[i]; za[8 + i] += (float)z1[i];
                    pa[i] += (float)p0[i]; pa[8 + i] += (float)p1[i];
                }
            }
            half8 oz0, oz1, op0, op1;
            #pragma unroll
            for (int i = 0; i < 8; ++i) {
                oz0[i] = (_Float16)za[i];     oz1[i] = (_Float16)za[8 + i];
                op0[i] = (_Float16)pa[i];     op1[i] = (_Float16)pa[8 + i];
            }
            *(half8*)&Apanel[r * 264 + p * 16]           = oz0;
            *(half8*)&Apanel[r * 264 + p * 16 + 8]       = oz1;
            *(half8*)&Apanel[r * 264 + 128 + p * 16]     = op0;
            *(half8*)&Apanel[r * 264 + 128 + p * 16 + 8] = op1;
        }
    }
    __syncthreads();   // gather visible + chunk-0 DMA drained

    // ---- GEMM phase: reg-prefetch pipeline, single Blds buffer ----
    half8 pf0, pf1, pf2, pf3;
    auto pfetch = [&](int c) {
        const _Float16* s = W12P + (size_t)c * 8192 + (size_t)sb * 8;
        pf0 = *(const half8*)(s);
        pf1 = *(const half8*)(s + 512);
        pf2 = *(const half8*)(s + 1024);
        pf3 = *(const half8*)(s + 1536);
    };
    pfetch(1);

    f32x4 acc[4][4] = {};
    for (int c = 0; c < 16; ++c) {
        const int kl = (c & 7) * 32;
        half8 a[4], b[4];
        #pragma unroll
        for (int i = 0; i < 4; ++i)
            a[i] = *(const half8*)&Apanel[(i * 16 + l16) * 264 + kl + q * 8];
        #pragma unroll
        for (int j = 0; j < 4; ++j)
            b[j] = *(const half8*)&Blds[(q * 256 + nbase + j * 16 + l16) * 8];
        #pragma unroll
        for (int i = 0; i < 4; ++i)
            #pragma unroll
            for (int j = 0; j < 4; ++j)
                acc[i][j] = __builtin_amdgcn_mfma_f32_16x16x32_f16(a[i], b[j], acc[i][j], 0, 0, 0);
        if (c == 15) break;
        __syncthreads();                    // all waves done reading chunk c
        *(half8*)&Blds[sb * 8]         = pf0;   // write chunk c+1
        *(half8*)&Blds[(sb + 64) * 8]  = pf1;
        *(half8*)&Blds[(sb + 128) * 8] = pf2;
        *(half8*)&Blds[(sb + 192) * 8] = pf3;
        if (c == 7) {
            // H1 = relu(X@W1 + b1) writeback (Apanel readers past barrier)
            #pragma unroll
            for (int j = 0; j < 4; ++j) {
                const int colg = nbase + j * 16 + l16;
                const float bv = b1[colg];
                #pragma unroll
                for (int i = 0; i < 4; ++i)
                    #pragma unroll
                    for (int rr = 0; rr < 4; ++rr) {
                        const float v = fmaxf(acc[i][j][rr] + bv, 0.0f);
                        Apanel[(i * 16 + q * 4 + rr) * 264 + colg] = (_Float16)v;
                        acc[i][j][rr] = 0.0f;
                    }
            }
        }
        if (c < 14) pfetch(c + 2);          // loads fly over next MFMA
        __syncthreads();                    // chunk c+1 / Apanel visible
    }

    #pragma unroll
    for (int j = 0; j < 4; ++j) {
        const int colg = nbase + j * 16 + l16;
        const float bv = b2[colg];
        #pragma unroll
        for (int i = 0; i < 4; ++i)
            #pragma unroll
            for (int rr = 0; rr < 4; ++rr) {
                const int rowg = bm + i * 16 + q * 4 + rr;
                H[(size_t)rowg * HID + colg] = (_Float16)(acc[i][j][rr] + bv);
            }
    }
}

// ---------------------------------------------------------------------------
// 5. CSR gather-aggregation (SAGE mean): 32 lanes/row, 8-edge unroll.
// ---------------------------------------------------------------------------
__global__ __launch_bounds__(256) void csr_agg_kernel(
    const int* __restrict__ row_ptr, const int* __restrict__ col,
    const _Float16* __restrict__ F, _Float16* __restrict__ OUT)
{
    const int t = blockIdx.x * 256 + threadIdx.x;
    const int d = t >> 5;
    const int q = t & 31;
    const int beg = row_ptr[d];
    const int end = row_ptr[d + 1];
    float acc[8] = {0.f,0.f,0.f,0.f,0.f,0.f,0.f,0.f};
    int e = beg;
    for (; e + 8 <= end; e += 8) {
        const int s0 = col[e],     s1 = col[e + 1];
        const int s2 = col[e + 2], s3 = col[e + 3];
        const int s4 = col[e + 4], s5 = col[e + 5];
        const int s6 = col[e + 6], s7 = col[e + 7];
        const half8 v0 = *(const half8*)(F + (size_t)s0 * HID + q * 8);
        const half8 v1 = *(const half8*)(F + (size_t)s1 * HID + q * 8);
        const half8 v2 = *(const half8*)(F + (size_t)s2 * HID + q * 8);
        const half8 v3 = *(const half8*)(F + (size_t)s3 * HID + q * 8);
        const half8 v4 = *(const half8*)(F + (size_t)s4 * HID + q * 8);
        const half8 v5 = *(const half8*)(F + (size_t)s5 * HID + q * 8);
        const half8 v6 = *(const half8*)(F + (size_t)s6 * HID + q * 8);
        const half8 v7 = *(const half8*)(F + (size_t)s7 * HID + q * 8);
        #pragma unroll
        for (int i = 0; i < 8; ++i)
            acc[i] += (((float)v0[i] + (float)v1[i]) + ((float)v2[i] + (float)v3[i]))
                    + (((float)v4[i] + (float)v5[i]) + ((float)v6[i] + (float)v7[i]));
    }
    for (; e + 4 <= end; e += 4) {
        const int s0 = col[e],     s1 = col[e + 1];
        const int s2 = col[e + 2], s3 = col[e + 3];
        const half8 v0 = *(const half8*)(F + (size_t)s0 * HID + q * 8);
        const half8 v1 = *(const half8*)(F + (size_t)s1 * HID + q * 8);
        const half8 v2 = *(const half8*)(F + (size_t)s2 * HID + q * 8);
        const half8 v3 = *(const half8*)(F + (size_t)s3 * HID + q * 8);
        #pragma unroll
        for (int i = 0; i < 8; ++i)
            acc[i] += ((float)v0[i] + (float)v1[i]) + ((float)v2[i] + (float)v3[i]);
    }
    for (; e < end; ++e) {
        const half8 v0 = *(const half8*)(F + (size_t)col[e] * HID + q * 8);
        #pragma unroll
        for (int i = 0; i < 8; ++i) acc[i] += (float)v0[i];
    }
    const float rs = 1.0f / fmaxf((float)(end - beg), 1.0f);
    half8 o;
    #pragma unroll
    for (int i = 0; i < 8; ++i) o[i] = (_Float16)(acc[i] * rs);
    *(half8*)(OUT + (size_t)d * HID + q * 8) = o;
}

// ---------------------------------------------------------------------------
// 6. MFMA f16 GEMM (SAGE): C = [A1|A2] @ [B1;B2] + bias, K=512 -> f16.
//    R8's proven 128x128 body; only the block->tile mapping changed: the two
//    N-tiles of each M-row run as blocks 8 apart (same XCD, back-to-back),
//    so the 64KB A-panel's second read hits that XCD's L2 (A fabric traffic
//    128 -> ~64 MB).
// ---------------------------------------------------------------------------
__global__ __launch_bounds__(256) void mfma_gemm_kernel(
    const _Float16* __restrict__ A1, const _Float16* __restrict__ A2,
    const _Float16* __restrict__ B1T, const _Float16* __restrict__ B2T,
    const float* __restrict__ bias, _Float16* __restrict__ Ch)
{
    __shared__ _Float16 Alds[128 * 32];
    __shared__ _Float16 Blds[128 * 32];
    const int bid  = blockIdx.x;                    // 0..1023
    const int m    = (bid >> 4) * 8 + (bid & 7);    // 0..511
    const int n    = (bid >> 3) & 1;                // 0..1
    const int bm   = m * 128;
    const int bn   = n * 128;
    const int tid  = threadIdx.x;
    const int wave = tid >> 6, lane = tid & 63;
    const int q    = lane >> 4, l16 = lane & 15;
    const int mbase = (wave & 1) * 64, nbase = (wave >> 1) * 64;

    const int i0 = wave * 128 + lane;
    const int i1 = i0 + 64;
    const int r0 = i0 >> 2, s0 = i0 & 3;
    const int r1 = i1 >> 2, s1 = i1 & 3;

    half8 pa0, pa1, pb0, pb1;
    auto pfetch = [&](int kc) {
        const int k0 = (kc & 7) * 32;
        const _Float16* Ab = (kc < 8) ? A1 : A2;
        const _Float16* Bb = (kc < 8) ? B1T : B2T;
        pa0 = *(const half8*)(Ab + (size_t)(bm + r0) * HID + k0 + s0 * 8);
        pa1 = *(const half8*)(Ab + (size_t)(bm + r1) * HID + k0 + s1 * 8);
        pb0 = *(const half8*)(Bb + (size_t)(bn + r0) * HID + k0 + s0 * 8);
        pb1 = *(const half8*)(Bb + (size_t)(bn + r1) * HID + k0 + s1 * 8);
    };
    pfetch(0);

    f32x4 acc[4][4] = {};

    for (int kc = 0; kc < 16; ++kc) {
        __syncthreads();
        *(half8*)&Alds[i0 * 8] = pa0;
        *(half8*)&Alds[i1 * 8] = pa1;
        *(half8*)&Blds[i0 * 8] = pb0;
        *(half8*)&Blds[i1 * 8] = pb1;
        if (kc < 15) pfetch(kc + 1);
        __syncthreads();
        half8 a[4], b[4];
        #pragma unroll
        for (int i = 0; i < 4; ++i)
            a[i] = *(const half8*)&Alds[(mbase + i * 16 + l16) * 32 + q * 8];
        #pragma unroll
        for (int j = 0; j < 4; ++j)
            b[j] = *(const half8*)&Blds[(nbase + j * 16 + l16) * 32 + q * 8];
        #pragma unroll
        for (int i = 0; i < 4; ++i)
            #pragma unroll
            for (int j = 0; j < 4; ++j)
                acc[i][j] = __builtin_amdgcn_mfma_f32_16x16x32_f16(a[i], b[j], acc[i][j], 0, 0, 0);
    }

    #pragma unroll
    for (int j = 0; j < 4; ++j) {
        const int colg = bn + nbase + j * 16 + l16;
        const float bv = bias[colg];
        #pragma unroll
        for (int i = 0; i < 4; ++i) {
            #pragma unroll
            for (int rr = 0; rr < 4; ++rr) {
                const int rowg = bm + mbase + i * 16 + q * 4 + rr;
                Ch[(size_t)rowg * HID + colg] = (_Float16)(acc[i][j][rr] + bv);
            }
        }
    }
}

// ---------------------------------------------------------------------------
// 7. Fused max-pool + head MLP: one block per graph.
// ---------------------------------------------------------------------------
__global__ __launch_bounds__(256) void pool_head_kernel(
    const _Float16* __restrict__ H2, const int* __restrict__ gid,
    const float* __restrict__ W1, const float* __restrict__ b1,
    const float* __restrict__ W2, const float* __restrict__ b2,
    float* __restrict__ out)
{
    const int g = blockIdx.x;
    const int tid = threadIdx.x;
    int lo = 0, hi = N_NODES;
    while (lo < hi) { const int mid = (lo + hi) >> 1; if (gid[mid] < g) lo = mid + 1; else hi = mid; }
    const int start = lo;
    hi = N_NODES;
    while (lo < hi) { const int mid = (lo + hi) >> 1; if (gid[mid] < g + 1) lo = mid + 1; else hi = mid; }
    const int end = lo;

    const int rowofs = tid >> 5;        // 0..7
    const int q = tid & 31;             // half8 col slice
    float m8[8];
    #pragma unroll
    for (int k = 0; k < 8; ++k) m8[k] = -INFINITY;
    for (int i = start + rowofs; i < end; i += 8) {
        const half8 v = *(const half8*)(H2 + (size_t)i * HID + q * 8);
        #pragma unroll
        for (int k = 0; k < 8; ++k) m8[k] = fmaxf(m8[k], (float)v[k]);
    }
    __shared__ float part[8][256];
    #pragma unroll
    for (int k = 0; k < 8; ++k) part[rowofs][q * 8 + k] = m8[k];
    __syncthreads();
    __shared__ float row[HID];
    __shared__ float red[HID];
    const int j = tid;
    float m = part[0][j];
    #pragma unroll
    for (int r = 1; r < 8; ++r) m = fmaxf(m, part[r][j]);
    row[j] = (m == -INFINITY) ? 0.0f : m;
    __syncthreads();
    float acc = b1[j];
    #pragma unroll 8
    for (int k = 0; k < HID; ++k)
        acc = fmaf(row[k], W1[k * HID + j], acc);
    acc = fmaxf(acc, 0.f);
    red[j] = acc * W2[j];
    __syncthreads();
    for (int s = 128; s > 0; s >>= 1) {
        if (j < s) red[j] += red[j + s];
        __syncthreads();
    }
    if (j == 0) out[g] = red[0] + b2[0];
}

// ---------------------------------------------------------------------------
extern "C" void kernel_launch(void* const* d_in, const int* in_sizes, int n_in,
                              void* d_out, int out_size, void* d_ws, size_t ws_size,
                              hipStream_t stream)
{
    const int*   z         = (const int*)d_in[0];
    const int*   node_id   = (const int*)d_in[1];
    const int*   src       = (const int*)d_in[2];
    const int*   dst       = (const int*)d_in[3];
    const int*   graph_ids = (const int*)d_in[4];
    const float* z_table   = (const float*)d_in[5];
    const float* d_feat    = (const float*)d_in[6];
    const float* c_feat    = (const float*)d_in[7];
    const float* Wd        = (const float*)d_in[8];
    const float* Wc        = (const float*)d_in[9];
    const float* gin_W1    = (const float*)d_in[10];
    const float* gin_b1    = (const float*)d_in[11];
    const float* gin_W2    = (const float*)d_in[12];
    const float* gin_b2    = (const float*)d_in[13];
    const float* sage_Wself  = (const float*)d_in[14];
    const float* sage_Wneigh = (const float*)d_in[15];
    const float* sage_b    = (const float*)d_in[16];
    const float* lin1_W    = (const float*)d_in[17];
    const float* lin1_b    = (const float*)d_in[18];
    const float* lin2_W    = (const float*)d_in[19];
    const float* lin2_b    = (const float*)d_in[20];
    float* out = (float*)d_out;

    // ---- workspace carve-up ----
    const size_t NH = (size_t)N_NODES * HID;
    char* wsb = (char*)d_ws;
    _Float16* Hh   = (_Float16*)wsb;                     wsb += NH * 2;
    _Float16* AGGh = (_Float16*)wsb;                     wsb += NH * 2;
    _Float16* H2h  = (_Float16*)wsb;                     wsb += NH * 2;
    _Float16* projh= (_Float16*)wsb;                     wsb += (size_t)G_NODES_N * IN_DIM * 2;
    _Float16* W12P = (_Float16*)wsb;                     wsb += 16 * 8192 * 2;
    _Float16* WsT  = (_Float16*)wsb;                     wsb += HID * HID * 2;
    _Float16* WnT  = (_Float16*)wsb;                     wsb += HID * HID * 2;
    _Float16* WdT  = (_Float16*)wsb;                     wsb += D_FEAT * IN_DIM * 2;
    _Float16* WcT  = (_Float16*)wsb;                     wsb += D_FEAT * IN_DIM * 2;
    _Float16* zt16 = (_Float16*)wsb;                     wsb += (size_t)MAX_Z * IN_DIM * 2;
    int2* zn2      = (int2*)wsb;                         wsb += (size_t)N_NODES * 8;
    int2* colzn    = (int2*)wsb;                         wsb += (size_t)(N_EDGES + 8) * 8;
    int* row_ptr   = (int*)wsb;                          wsb += (N_NODES + 4) * 4;
    int* cnt       = (int*)wsb;                          wsb += N_NODES * 4;
    int* fill      = (int*)wsb;                          wsb += N_NODES * 4;
    int* col       = (int*)wsb;                          wsb += N_EDGES * 4;
    int* flags     = (int*)wsb;                          wsb += 128 * 4;

    // ---- zero cnt/flags (graph-capturable), then prep + histogram ----
    hipMemsetAsync(cnt, 0, N_NODES * sizeof(int), stream);
    hipMemsetAsync(flags, 0, 128 * sizeof(int), stream);
    prep_hist_kernel<<<1082 + N_EDGES / 256, 256, 0, stream>>>(
        sage_Wself, sage_Wneigh, Wd, Wc, gin_W1, gin_W2, z_table, z, node_id,
        dst, WsT, WnT, WdT, WcT, W12P, zt16, zn2, cnt);

    // ---- CSR scan ----
    scan_fused_kernel<<<64, 256, 0, stream>>>(cnt, row_ptr, fill, flags);

    // ---- scatter (2048 blocks) + projection GEMM (79 blocks) merged ----
    scatter_proj_kernel<<<79 + N_EDGES / 256, 256, 0, stream>>>(
        d_feat, c_feat, WdT, WcT, projh, src, dst, zn2, fill, col, colzn);

    // ---- fused GIN: gather + MLP, H1 stays in LDS (M=64 rows/block) ----
    gin_fused_kernel<<<N_NODES / 64, 256, 0, stream>>>(
        row_ptr, colzn, zn2, zt16, projh, W12P, gin_b1, gin_b2, Hh);

    // ---- SAGE mean aggregation ----
    csr_agg_kernel<<<(N_NODES * 32) / 256, 256, 0, stream>>>(row_ptr, col, Hh, AGGh);

    // ---- SAGE: H2 = H@Wself + AGG@Wneigh + b  (K=512, XCD-paired tiles) ----
    mfma_gemm_kernel<<<1024, 256, 0, stream>>>(
        Hh, AGGh, WsT, WnT, sage_b, H2h);

    // ---- fused max pool + head ----
    pool_head_kernel<<<N_GRAPHS, 256, 0, stream>>>(
        H2h, graph_ids, lin1_W, lin1_b, lin2_W, lin2_b, out);
}